// Round 4
// baseline (371.164 us; speedup 1.0000x reference)
//
#include <hip/hip_runtime.h>
#include <math.h>

// Problem constants
#define BSZ   2
#define NTOK  1024          // 32*32
#define CDIM  512
#define SENC  77
#define SKV   1101          // 77 + 1024
#define ENCD  768
#define NHEAD 64
#define DHEAD 8

typedef short short8 __attribute__((ext_vector_type(8)));
typedef float floatx4 __attribute__((ext_vector_type(4)));

__device__ __forceinline__ unsigned short f2bf(float f) {
    union { float f; unsigned int u; } v; v.f = f;
    unsigned int r = v.u + 0x7FFF + ((v.u >> 16) & 1);   // RNE
    return (unsigned short)(r >> 16);
}

// C-style casts: clang only allows addrspacecast via C-style
__device__ __forceinline__ void gld16(const void* g, void* l) {
    __builtin_amdgcn_global_load_lds(
        (const __attribute__((address_space(1))) unsigned int*)g,
        (__attribute__((address_space(3))) unsigned int*)l,
        16, 0, 0);
}

// ---------------------------------------------------------------- reductions
__device__ __forceinline__ float block_reduce_sum(float v) {
    #pragma unroll
    for (int off = 32; off > 0; off >>= 1) v += __shfl_down(v, off, 64);
    __shared__ float tmp[4];
    int lane = threadIdx.x & 63, wid = threadIdx.x >> 6;
    if (lane == 0) tmp[wid] = v;
    __syncthreads();
    if (wid == 0) {
        float r = (lane < 4) ? tmp[lane] : 0.f;
        r += __shfl_down(r, 2, 64);
        r += __shfl_down(r, 1, 64);
        if (lane == 0) tmp[0] = r;
    }
    __syncthreads();
    float out = tmp[0];
    __syncthreads();
    return out;
}

// ---------------------------------------------------------------- prep device parts
__device__ void layernorm_dev(int row, const float* __restrict__ x,
                              const float* __restrict__ sc, const float* __restrict__ bi,
                              unsigned short* __restrict__ out) {
    const float* xp = x + (size_t)row * ENCD;
    unsigned short* op = out + (size_t)row * ENCD;
    int t = threadIdx.x;
    float v0 = xp[t], v1 = xp[t + 256], v2 = xp[t + 512];
    float mu = block_reduce_sum(v0 + v1 + v2) * (1.f / ENCD);
    float d0 = v0 - mu, d1 = v1 - mu, d2 = v2 - mu;
    float var = block_reduce_sum(d0 * d0 + d1 * d1 + d2 * d2) * (1.f / ENCD);
    float rstd = rsqrtf(var + 1e-5f);
    op[t]       = f2bf(d0 * rstd * sc[t]       + bi[t]);
    op[t + 256] = f2bf(d1 * rstd * sc[t + 256] + bi[t + 256]);
    op[t + 512] = f2bf(d2 * rstd * sc[t + 512] + bi[t + 512]);
}

__device__ void groupnorm_dev(int bg, const float* __restrict__ x,
                              const float* __restrict__ sc, const float* __restrict__ bi,
                              unsigned short* __restrict__ out) {
    int b = bg >> 5, g = bg & 31;
    const float* xp = x + (size_t)b * NTOK * CDIM + g * 16;
    unsigned short* op = out + (size_t)b * NTOK * CDIM + g * 16;
    int t = threadIdx.x;

    float s = 0.f;
    for (int idx = t; idx < 4096; idx += 256) {
        int n = idx >> 2, q = idx & 3;
        float4 v = *(const float4*)(xp + n * CDIM + q * 4);
        s += (v.x + v.y) + (v.z + v.w);
    }
    float mu = block_reduce_sum(s) * (1.f / 16384.f);

    float vs = 0.f;
    for (int idx = t; idx < 4096; idx += 256) {
        int n = idx >> 2, q = idx & 3;
        float4 v = *(const float4*)(xp + n * CDIM + q * 4);
        float dx = v.x - mu, dy = v.y - mu, dz = v.z - mu, dw = v.w - mu;
        vs += (dx * dx + dy * dy) + (dz * dz + dw * dw);
    }
    float var = block_reduce_sum(vs) * (1.f / 16384.f);
    float rstd = rsqrtf(var + 1e-5f);

    for (int idx = t; idx < 4096; idx += 256) {
        int n = idx >> 2, q = idx & 3;
        float4 v = *(const float4*)(xp + n * CDIM + q * 4);
        float4 s4 = *(const float4*)(sc + g * 16 + q * 4);
        float4 b4 = *(const float4*)(bi + g * 16 + q * 4);
        ushort4 o;
        o.x = f2bf((v.x - mu) * rstd * s4.x + b4.x);
        o.y = f2bf((v.y - mu) * rstd * s4.y + b4.y);
        o.z = f2bf((v.z - mu) * rstd * s4.z + b4.z);
        o.w = f2bf((v.w - mu) * rstd * s4.w + b4.w);
        *(ushort4*)(op + n * CDIM + q * 4) = o;
    }
}

// transpose+cast one 32x32 tile: W[K][N] fp32 -> Wt[N+roff][K] bf16
__device__ void tcast_dev(const float* __restrict__ W, unsigned short* __restrict__ Wt,
                          int K, int N, int roff, int local) {
    __shared__ float t[32][33];
    int bn = (local & 15) * 32, bk = (local >> 4) * 32;
    int lx = threadIdx.x & 31, ly = threadIdx.x >> 5;
    #pragma unroll
    for (int r = 0; r < 4; ++r)
        t[ly + 8 * r][lx] = W[(size_t)(bk + ly + 8 * r) * N + bn + lx];
    __syncthreads();
    #pragma unroll
    for (int r = 0; r < 4; ++r)
        Wt[(size_t)(roff + bn + ly + 8 * r) * K + bk + lx] = f2bf(t[lx][ly + 8 * r]);
}

// ---------------------------------------------------------------- fused preprocessing
__global__ __launch_bounds__(256) void prep_all(
        const float* __restrict__ Wq, const float* __restrict__ Wk, const float* __restrict__ Wv,
        const float* __restrict__ Wak, const float* __restrict__ Wav, const float* __restrict__ Wo,
        const float* __restrict__ bq, const float* __restrict__ bk, const float* __restrict__ bv,
        const float* __restrict__ bak, const float* __restrict__ bav,
        const float* __restrict__ enc, const float* __restrict__ ln_s, const float* __restrict__ ln_b,
        const float* __restrict__ x, const float* __restrict__ gn_s, const float* __restrict__ gn_b,
        unsigned short* __restrict__ Wqkv_t, unsigned short* __restrict__ Wakv_t,
        unsigned short* __restrict__ Wo_t,
        float* __restrict__ bqkv, float* __restrict__ bakv,
        unsigned short* __restrict__ enc_bf, unsigned short* __restrict__ hs_bf) {
    int bid = blockIdx.x;
    if (bid < 256)        tcast_dev(Wq,  Wqkv_t, 512, 512, 0,    bid);
    else if (bid < 512)   tcast_dev(Wk,  Wqkv_t, 512, 512, 512,  bid - 256);
    else if (bid < 768)   tcast_dev(Wv,  Wqkv_t, 512, 512, 1024, bid - 512);
    else if (bid < 1152)  tcast_dev(Wak, Wakv_t, 768, 512, 0,    bid - 768);
    else if (bid < 1536)  tcast_dev(Wav, Wakv_t, 768, 512, 512,  bid - 1152);
    else if (bid < 1792)  tcast_dev(Wo,  Wo_t,   512, 512, 0,    bid - 1536);
    else if (bid < 1802) {
        int i = (bid - 1792) * 256 + threadIdx.x;
        if (i < 512)        bqkv[i] = bq[i];
        else if (i < 1024)  bqkv[i] = bk[i - 512];
        else if (i < 1536)  bqkv[i] = bv[i - 1024];
        else if (i < 2048)  bakv[i - 1536] = bak[i - 1536];
        else if (i < 2560)  bakv[i - 1536] = bav[i - 2048];
    }
    else if (bid < 1956)  layernorm_dev(bid - 1802, enc, ln_s, ln_b, enc_bf);
    else                  groupnorm_dev(bid - 1956, x, gn_s, gn_b, hs_bf);
}

// ---------------------------------------------------------------- bf16 MFMA GEMM
// D[M,N] = A[M,K](bf16) @ Bt[N,K](bf16)^T + bias.  128x128 block, 4 waves 2x2.
template <int EPI>
__global__ __launch_bounds__(256) void mfma_gemm(
        const unsigned short* __restrict__ A, int Mv,
        const unsigned short* __restrict__ Bt,
        const float* __restrict__ bias,
        float* __restrict__ out, int ldo, int K,
        const float* __restrict__ resid) {
    __shared__ alignas(16) unsigned short AsS[128 * 32];
    __shared__ alignas(16) unsigned short BsS[128 * 32];
    int tid = threadIdx.x;
    int wv = tid >> 6, ln = tid & 63;
    int quad = ln >> 4, l16 = ln & 15;
    int wr = wv >> 1, wc = wv & 1;
    int n0 = blockIdx.x * 128, m0 = blockIdx.y * 128;

    floatx4 acc[4][4] = {};

    for (int k0 = 0; k0 < K; k0 += 32) {
        #pragma unroll
        for (int it = 0; it < 2; ++it) {
            int cb = it * 256 + wv * 64;
            int c = cb + ln;
            int r = c >> 2, sg = c & 3;
            int row = m0 + r; if (row > Mv - 1) row = Mv - 1;
            const unsigned short* ga = A + (size_t)row * K + k0 + sg * 8;
            gld16((const void*)ga, (void*)((char*)AsS + cb * 16));
            const unsigned short* gb = Bt + (size_t)(n0 + r) * K + k0 + sg * 8;
            gld16((const void*)gb, (void*)((char*)BsS + cb * 16));
        }
        __syncthreads();
        short8 af[4], bf[4];
        #pragma unroll
        for (int i = 0; i < 4; ++i)
            af[i] = *(const short8*)(AsS + (wr * 64 + i * 16 + l16) * 32 + quad * 8);
        #pragma unroll
        for (int j = 0; j < 4; ++j)
            bf[j] = *(const short8*)(BsS + (wc * 64 + j * 16 + l16) * 32 + quad * 8);
        #pragma unroll
        for (int i = 0; i < 4; ++i)
            #pragma unroll
            for (int j = 0; j < 4; ++j)
                acc[i][j] = __builtin_amdgcn_mfma_f32_16x16x32_bf16(af[i], bf[j], acc[i][j], 0, 0, 0);
        __syncthreads();
    }

    if (EPI == 0) {
        #pragma unroll
        for (int i = 0; i < 4; ++i) {
            int rbase = m0 + wr * 64 + i * 16 + quad * 4;
            #pragma unroll
            for (int j = 0; j < 4; ++j) {
                int col = n0 + wc * 64 + j * 16 + l16;
                float bcol = bias[col];
                #pragma unroll
                for (int r = 0; r < 4; ++r) {
                    int row = rbase + r;
                    if (row < Mv) out[(size_t)row * ldo + col] = acc[i][j][r] + bcol;
                }
            }
        }
    } else {
        #pragma unroll
        for (int i = 0; i < 4; ++i) {
            int cbase = m0 + wr * 64 + i * 16 + quad * 4;
            #pragma unroll
            for (int j = 0; j < 4; ++j) {
                int ng = n0 + wc * 64 + j * 16 + l16;
                int b = ng >> 10, n = ng & 1023;
                float4 res = *(const float4*)(resid + ((size_t)(b * 1024 + n)) * 512 + cbase);
                float rr[4] = {res.x, res.y, res.z, res.w};
                #pragma unroll
                for (int r = 0; r < 4; ++r) {
                    int c = cbase + r;
                    out[((size_t)(b * 512 + c)) * 1024 + n] = acc[i][j][r] + bias[c] + rr[r];
                }
            }
        }
    }
}

// ---------------------------------------------------------------- attention
// 1 thread = 1 query; K/V read directly from global with WAVE-UNIFORM addresses
// (scalarizable to s_load / single coalesced request). No LDS, no barriers.
// V row always at K row + 512 in both fused layouts.
template <int STRIDE, bool MASK>
__device__ __forceinline__ void attn_chunk(
        const float* __restrict__ baseK, int j0, int jmax,
        float4 q0, float4 q1, float& m, float& l, float (&a)[8]) {
    float s[8];
    #pragma unroll
    for (int t = 0; t < 8; ++t) {
        int j = j0 + t;
        int jc = MASK ? (j < jmax ? j : jmax - 1) : j;
        const float* kp = baseK + (size_t)jc * STRIDE;
        float4 k0 = *(const float4*)kp;
        float4 k1 = *(const float4*)(kp + 4);
        float d = q0.x * k0.x + q0.y * k0.y + q0.z * k0.z + q0.w * k0.w
                + q1.x * k1.x + q1.y * k1.y + q1.z * k1.z + q1.w * k1.w;
        s[t] = (!MASK || j < jmax) ? d : -INFINITY;
    }
    float cm = fmaxf(fmaxf(fmaxf(s[0], s[1]), fmaxf(s[2], s[3])),
                     fmaxf(fmaxf(s[4], s[5]), fmaxf(s[6], s[7])));
    float mn = fmaxf(m, cm);
    float corr = __builtin_amdgcn_exp2f(m - mn);
    float p[8];
    #pragma unroll
    for (int t = 0; t < 8; ++t) p[t] = __builtin_amdgcn_exp2f(s[t] - mn);
    float ps = ((p[0] + p[1]) + (p[2] + p[3])) + ((p[4] + p[5]) + (p[6] + p[7]));
    l = l * corr + ps;
    m = mn;
    #pragma unroll
    for (int r = 0; r < 8; ++r) a[r] *= corr;
    #pragma unroll
    for (int t = 0; t < 8; ++t) {
        int j = j0 + t;
        int jc = MASK ? (j < jmax ? j : jmax - 1) : j;
        const float* vp = baseK + (size_t)jc * STRIDE + 512;
        float4 v0 = *(const float4*)vp;
        float4 v1 = *(const float4*)(vp + 4);
        a[0] = fmaf(p[t], v0.x, a[0]); a[1] = fmaf(p[t], v0.y, a[1]);
        a[2] = fmaf(p[t], v0.z, a[2]); a[3] = fmaf(p[t], v0.w, a[3]);
        a[4] = fmaf(p[t], v1.x, a[4]); a[5] = fmaf(p[t], v1.y, a[5]);
        a[6] = fmaf(p[t], v1.z, a[6]); a[7] = fmaf(p[t], v1.w, a[7]);
    }
}

__global__ __launch_bounds__(256) void attn_kernel(
        const float* __restrict__ QKV, const float* __restrict__ EKV,
        unsigned short* __restrict__ AO) {
    int bh = blockIdx.x >> 2, qt = blockIdx.x & 3;
    int b = bh >> 6, h = bh & 63;
    int n = qt * 256 + threadIdx.x;
    int coff = h * DHEAD;

    const float* qp = QKV + ((size_t)(b * NTOK + n) * 1536 + coff);
    float4 q0 = *(const float4*)qp;
    float4 q1 = *(const float4*)(qp + 4);
    const float sc = 0.3535533905932738f * 1.4426950408889634f;  // 1/sqrt(8)*log2(e)
    q0.x *= sc; q0.y *= sc; q0.z *= sc; q0.w *= sc;
    q1.x *= sc; q1.y *= sc; q1.z *= sc; q1.w *= sc;

    float m = -INFINITY, l = 0.f;
    float a[8];
    #pragma unroll
    for (int r = 0; r < 8; ++r) a[r] = 0.f;

    // encoder segment: K rows at EKV[b][j][coff], V at +512
    const float* ebase = EKV + (size_t)b * SENC * 1024 + coff;
    for (int j0 = 0; j0 < SENC; j0 += 8)
        attn_chunk<1024, true>(ebase, j0, SENC, q0, q1, m, l, a);

    // self segment: K rows at QKV[b][j][512+coff], V at +512; 1024 = 128 clean chunks
    const float* sbase = QKV + (size_t)b * NTOK * 1536 + 512 + coff;
    for (int j0 = 0; j0 < NTOK; j0 += 8)
        attn_chunk<1536, false>(sbase, j0, NTOK, q0, q1, m, l, a);

    float inv = 1.f / l;
    union { unsigned short us[8]; uint4 v; } ou;
    #pragma unroll
    for (int r = 0; r < 8; ++r) ou.us[r] = f2bf(a[r] * inv);
    *(uint4*)(AO + ((size_t)(b * NTOK + n) * CDIM + coff)) = ou.v;
}

// ---------------------------------------------------------------- launcher
extern "C" void kernel_launch(void* const* d_in, const int* in_sizes, int n_in,
                              void* d_out, int out_size, void* d_ws, size_t ws_size,
                              hipStream_t stream) {
    const float* x    = (const float*)d_in[0];
    const float* enc  = (const float*)d_in[1];
    const float* gn_s = (const float*)d_in[2];
    const float* gn_b = (const float*)d_in[3];
    const float* ln_s = (const float*)d_in[4];
    const float* ln_b = (const float*)d_in[5];
    const float* Wq  = (const float*)d_in[6];   const float* bq  = (const float*)d_in[7];
    const float* Wk  = (const float*)d_in[8];   const float* bk  = (const float*)d_in[9];
    const float* Wv  = (const float*)d_in[10];  const float* bv  = (const float*)d_in[11];
    const float* Wak = (const float*)d_in[12];  const float* bak = (const float*)d_in[13];
    const float* Wav = (const float*)d_in[14];  const float* bav = (const float*)d_in[15];
    const float* Wo  = (const float*)d_in[16];  const float* bo  = (const float*)d_in[17];
    float* out = (float*)d_out;

    char* p = (char*)d_ws;
    auto alloc = [&](size_t bytes) { char* r = p; p += (bytes + 255) & ~255ULL; return r; };
    unsigned short* hs_bf  = (unsigned short*)alloc((size_t)2048 * 512 * 2);
    unsigned short* enc_bf = (unsigned short*)alloc((size_t)154 * 768 * 2);
    unsigned short* Wqkv_t = (unsigned short*)alloc((size_t)1536 * 512 * 2);
    unsigned short* Wakv_t = (unsigned short*)alloc((size_t)1024 * 768 * 2);
    unsigned short* Wo_t   = (unsigned short*)alloc((size_t)512 * 512 * 2);
    float* bqkv = (float*)alloc(1536 * 4);
    float* bakv = (float*)alloc(1024 * 4);
    float* QKV  = (float*)alloc((size_t)2048 * 1536 * 4);
    float* EKV  = (float*)alloc((size_t)154 * 1024 * 4);
    unsigned short* AO = (unsigned short*)alloc((size_t)2048 * 512 * 2);

    prep_all<<<2020, 256, 0, stream>>>(
        Wq, Wk, Wv, Wak, Wav, Wo, bq, bk, bv, bak, bav,
        enc, ln_s, ln_b, x, gn_s, gn_b,
        Wqkv_t, Wakv_t, Wo_t, bqkv, bakv, enc_bf, hs_bf);

    // QKV: [2048,512] x [512,1536]
    mfma_gemm<0><<<dim3(12, 16), 256, 0, stream>>>(hs_bf, 2048, Wqkv_t, bqkv, QKV, 1536, 512, nullptr);
    // enc K/V: [154,768] x [768,1024]
    mfma_gemm<0><<<dim3(8, 2), 256, 0, stream>>>(enc_bf, 154, Wakv_t, bakv, EKV, 1024, 768, nullptr);

    attn_kernel<<<BSZ * NHEAD * 4, 256, 0, stream>>>(QKV, EKV, AO);

    // out-proj as C^T: A=Wo_t [512,512], Bt=AO [2048,512] -> out [B,C,N] + bias + residual
    mfma_gemm<1><<<dim3(16, 4), 256, 0, stream>>>(Wo_t, 512, AO, bo, out, 1024, 512, x);

    (void)in_sizes; (void)n_in; (void)out_size; (void)ws_size;
}

// Round 5
// 265.017 us; speedup vs baseline: 1.4005x; 1.4005x over previous
//
#include <hip/hip_runtime.h>
#include <math.h>

// Problem constants
#define BSZ   2
#define NTOK  1024          // 32*32
#define CDIM  512
#define SENC  77
#define SKV   1101          // 77 + 1024 (order: self rows 0..1023, enc rows 1024..1100)
#define KROWS 1120          // padded KV rows (35 chunks of 32)
#define ENCD  768
#define NHEAD 64
#define DHEAD 8

typedef short short8 __attribute__((ext_vector_type(8)));
typedef float floatx4 __attribute__((ext_vector_type(4)));

__device__ __forceinline__ unsigned short f2bf(float f) {
    union { float f; unsigned int u; } v; v.f = f;
    unsigned int r = v.u + 0x7FFF + ((v.u >> 16) & 1);   // RNE
    return (unsigned short)(r >> 16);
}

// C-style casts: clang only allows addrspacecast via C-style
__device__ __forceinline__ void gld16(const void* g, void* l) {
    __builtin_amdgcn_global_load_lds(
        (const __attribute__((address_space(1))) unsigned int*)g,
        (__attribute__((address_space(3))) unsigned int*)l,
        16, 0, 0);
}

// ---------------------------------------------------------------- reductions
__device__ __forceinline__ float block_reduce_sum(float v) {
    #pragma unroll
    for (int off = 32; off > 0; off >>= 1) v += __shfl_down(v, off, 64);
    __shared__ float tmp[4];
    int lane = threadIdx.x & 63, wid = threadIdx.x >> 6;
    if (lane == 0) tmp[wid] = v;
    __syncthreads();
    if (wid == 0) {
        float r = (lane < 4) ? tmp[lane] : 0.f;
        r += __shfl_down(r, 2, 64);
        r += __shfl_down(r, 1, 64);
        if (lane == 0) tmp[0] = r;
    }
    __syncthreads();
    float out = tmp[0];
    __syncthreads();
    return out;
}

// ---------------------------------------------------------------- prep device parts
__device__ void layernorm_dev(int row, const float* __restrict__ x,
                              const float* __restrict__ sc, const float* __restrict__ bi,
                              unsigned short* __restrict__ out) {
    const float* xp = x + (size_t)row * ENCD;
    unsigned short* op = out + (size_t)row * ENCD;
    int t = threadIdx.x;
    float v0 = xp[t], v1 = xp[t + 256], v2 = xp[t + 512];
    float mu = block_reduce_sum(v0 + v1 + v2) * (1.f / ENCD);
    float d0 = v0 - mu, d1 = v1 - mu, d2 = v2 - mu;
    float var = block_reduce_sum(d0 * d0 + d1 * d1 + d2 * d2) * (1.f / ENCD);
    float rstd = rsqrtf(var + 1e-5f);
    op[t]       = f2bf(d0 * rstd * sc[t]       + bi[t]);
    op[t + 256] = f2bf(d1 * rstd * sc[t + 256] + bi[t + 256]);
    op[t + 512] = f2bf(d2 * rstd * sc[t + 512] + bi[t + 512]);
}

__device__ void groupnorm_dev(int bg, const float* __restrict__ x,
                              const float* __restrict__ sc, const float* __restrict__ bi,
                              unsigned short* __restrict__ out) {
    int b = bg >> 5, g = bg & 31;
    const float* xp = x + (size_t)b * NTOK * CDIM + g * 16;
    unsigned short* op = out + (size_t)b * NTOK * CDIM + g * 16;
    int t = threadIdx.x;

    float s = 0.f;
    for (int idx = t; idx < 4096; idx += 256) {
        int n = idx >> 2, q = idx & 3;
        float4 v = *(const float4*)(xp + n * CDIM + q * 4);
        s += (v.x + v.y) + (v.z + v.w);
    }
    float mu = block_reduce_sum(s) * (1.f / 16384.f);

    float vs = 0.f;
    for (int idx = t; idx < 4096; idx += 256) {
        int n = idx >> 2, q = idx & 3;
        float4 v = *(const float4*)(xp + n * CDIM + q * 4);
        float dx = v.x - mu, dy = v.y - mu, dz = v.z - mu, dw = v.w - mu;
        vs += (dx * dx + dy * dy) + (dz * dz + dw * dw);
    }
    float var = block_reduce_sum(vs) * (1.f / 16384.f);
    float rstd = rsqrtf(var + 1e-5f);

    for (int idx = t; idx < 4096; idx += 256) {
        int n = idx >> 2, q = idx & 3;
        float4 v = *(const float4*)(xp + n * CDIM + q * 4);
        float4 s4 = *(const float4*)(sc + g * 16 + q * 4);
        float4 b4 = *(const float4*)(bi + g * 16 + q * 4);
        ushort4 o;
        o.x = f2bf((v.x - mu) * rstd * s4.x + b4.x);
        o.y = f2bf((v.y - mu) * rstd * s4.y + b4.y);
        o.z = f2bf((v.z - mu) * rstd * s4.z + b4.z);
        o.w = f2bf((v.w - mu) * rstd * s4.w + b4.w);
        *(ushort4*)(op + n * CDIM + q * 4) = o;
    }
}

// transpose+cast one 32x32 tile: W[K][N] fp32 -> Wt[N+roff][K] bf16
__device__ void tcast_dev(const float* __restrict__ W, unsigned short* __restrict__ Wt,
                          int K, int N, int roff, int local) {
    __shared__ float t[32][33];
    int bn = (local & 15) * 32, bk = (local >> 4) * 32;
    int lx = threadIdx.x & 31, ly = threadIdx.x >> 5;
    #pragma unroll
    for (int r = 0; r < 4; ++r)
        t[ly + 8 * r][lx] = W[(size_t)(bk + ly + 8 * r) * N + bn + lx];
    __syncthreads();
    #pragma unroll
    for (int r = 0; r < 4; ++r)
        Wt[(size_t)(roff + bn + ly + 8 * r) * K + bk + lx] = f2bf(t[lx][ly + 8 * r]);
}

// ---------------------------------------------------------------- fused preprocessing
__global__ __launch_bounds__(256) void prep_all(
        const float* __restrict__ Wq, const float* __restrict__ Wk, const float* __restrict__ Wv,
        const float* __restrict__ Wak, const float* __restrict__ Wav, const float* __restrict__ Wo,
        const float* __restrict__ bq, const float* __restrict__ bk, const float* __restrict__ bv,
        const float* __restrict__ bak, const float* __restrict__ bav,
        const float* __restrict__ enc, const float* __restrict__ ln_s, const float* __restrict__ ln_b,
        const float* __restrict__ x, const float* __restrict__ gn_s, const float* __restrict__ gn_b,
        unsigned short* __restrict__ Wqkv_t, unsigned short* __restrict__ Wakv_t,
        unsigned short* __restrict__ Wo_t,
        float* __restrict__ bqkv, float* __restrict__ bakv,
        unsigned short* __restrict__ enc_bf, unsigned short* __restrict__ hs_bf) {
    int bid = blockIdx.x;
    if (bid < 256)        tcast_dev(Wq,  Wqkv_t, 512, 512, 0,    bid);
    else if (bid < 512)   tcast_dev(Wk,  Wqkv_t, 512, 512, 512,  bid - 256);
    else if (bid < 768)   tcast_dev(Wv,  Wqkv_t, 512, 512, 1024, bid - 512);
    else if (bid < 1152)  tcast_dev(Wak, Wakv_t, 768, 512, 0,    bid - 768);
    else if (bid < 1536)  tcast_dev(Wav, Wakv_t, 768, 512, 512,  bid - 1152);
    else if (bid < 1792)  tcast_dev(Wo,  Wo_t,   512, 512, 0,    bid - 1536);
    else if (bid < 1802) {
        int i = (bid - 1792) * 256 + threadIdx.x;
        if (i < 512)        bqkv[i] = bq[i];
        else if (i < 1024)  bqkv[i] = bk[i - 512];
        else if (i < 1536)  bqkv[i] = bv[i - 1024];
        else if (i < 2048)  bakv[i - 1536] = bak[i - 1536];
        else if (i < 2560)  bakv[i - 1536] = bav[i - 2048];
    }
    else if (bid < 1956)  layernorm_dev(bid - 1802, enc, ln_s, ln_b, enc_bf);
    else                  groupnorm_dev(bid - 1956, x, gn_s, gn_b, hs_bf);
}

// ---------------------------------------------------------------- bf16 MFMA GEMM
// D[M,N] = A[M,K](bf16) @ Bt[N,K](bf16)^T + bias.  128x128 block, 4 waves 2x2.
// EPI=1: out-proj: out[(b*512+row)*1024+n] = acc + bias[row] + resid  (fp32)
// EPI=2: QKV epilogue -> Qb (scaled bf16), Kcat self rows, Vt transposed
// EPI=3: enc KV epilogue -> Kcat enc rows (1024+j), Vt enc cols
template <int EPI>
__global__ __launch_bounds__(256) void mfma_gemm(
        const unsigned short* __restrict__ A, int Mv,
        const unsigned short* __restrict__ Bt,
        const float* __restrict__ bias, int K,
        unsigned short* __restrict__ Qb, unsigned short* __restrict__ Kcat,
        unsigned short* __restrict__ Vt,
        float* __restrict__ out, const float* __restrict__ resid) {
    __shared__ alignas(16) unsigned short AsS[128 * 32];
    __shared__ alignas(16) unsigned short BsS[128 * 32];
    int tid = threadIdx.x;
    int wv = tid >> 6, ln = tid & 63;
    int quad = ln >> 4, l16 = ln & 15;
    int wr = wv >> 1, wc = wv & 1;
    int n0 = blockIdx.x * 128, m0 = blockIdx.y * 128;

    floatx4 acc[4][4] = {};

    for (int k0 = 0; k0 < K; k0 += 32) {
        #pragma unroll
        for (int it = 0; it < 2; ++it) {
            int cb = it * 256 + wv * 64;
            int c = cb + ln;
            int r = c >> 2, sg = c & 3;
            int row = m0 + r; if (row > Mv - 1) row = Mv - 1;
            const unsigned short* ga = A + (size_t)row * K + k0 + sg * 8;
            gld16((const void*)ga, (void*)((char*)AsS + cb * 16));
            const unsigned short* gb = Bt + (size_t)(n0 + r) * K + k0 + sg * 8;
            gld16((const void*)gb, (void*)((char*)BsS + cb * 16));
        }
        __syncthreads();
        short8 af[4], bf[4];
        #pragma unroll
        for (int i = 0; i < 4; ++i)
            af[i] = *(const short8*)(AsS + (wr * 64 + i * 16 + l16) * 32 + quad * 8);
        #pragma unroll
        for (int j = 0; j < 4; ++j)
            bf[j] = *(const short8*)(BsS + (wc * 64 + j * 16 + l16) * 32 + quad * 8);
        #pragma unroll
        for (int i = 0; i < 4; ++i)
            #pragma unroll
            for (int j = 0; j < 4; ++j)
                acc[i][j] = __builtin_amdgcn_mfma_f32_16x16x32_bf16(af[i], bf[j], acc[i][j], 0, 0, 0);
        __syncthreads();
    }

    const float ASCALE = 0.3535533905932738f * 1.4426950408889634f;  // 1/sqrt(8)*log2(e)

    if (EPI == 1) {
        // rows are channels c (Mv=512), cols are global tokens n_g (N=2048)
        #pragma unroll
        for (int i = 0; i < 4; ++i) {
            int cbase = m0 + wr * 64 + i * 16 + quad * 4;
            #pragma unroll
            for (int j = 0; j < 4; ++j) {
                int ng = n0 + wc * 64 + j * 16 + l16;
                int b = ng >> 10, n = ng & 1023;
                float4 res = *(const float4*)(resid + ((size_t)(b * 1024 + n)) * 512 + cbase);
                float rr[4] = {res.x, res.y, res.z, res.w};
                #pragma unroll
                for (int r = 0; r < 4; ++r) {
                    int c = cbase + r;
                    out[((size_t)(b * 512 + c)) * 1024 + n] = acc[i][j][r] + bias[c] + rr[r];
                }
            }
        }
    } else if (EPI == 2) {
        // rows = tokens (2048), cols: [0,512)=Q, [512,1024)=K, [1024,1536)=V
        #pragma unroll
        for (int i = 0; i < 4; ++i) {
            int t0 = m0 + wr * 64 + i * 16 + quad * 4;   // 4 consecutive tokens
            int b_ = t0 >> 10, nn = t0 & 1023;
            #pragma unroll
            for (int j = 0; j < 4; ++j) {
                int col = n0 + wc * 64 + j * 16 + l16;
                float v0 = acc[i][j][0] + bias[col];
                float v1 = acc[i][j][1] + bias[col];
                float v2 = acc[i][j][2] + bias[col];
                float v3 = acc[i][j][3] + bias[col];
                if (col < 512) {
                    unsigned short* qp = Qb + ((size_t)(b_ * 1024 + nn)) * 512 + col;
                    qp[0]       = f2bf(v0 * ASCALE);
                    qp[512]     = f2bf(v1 * ASCALE);
                    qp[1024]    = f2bf(v2 * ASCALE);
                    qp[1536]    = f2bf(v3 * ASCALE);
                } else if (col < 1024) {
                    int c = col - 512;
                    unsigned short* kp = Kcat + ((size_t)b_ * KROWS + nn) * 512 + c;
                    kp[0]    = f2bf(v0);
                    kp[512]  = f2bf(v1);
                    kp[1024] = f2bf(v2);
                    kp[1536] = f2bf(v3);
                } else {
                    int c = col - 1024;
                    ushort4 pk = { f2bf(v0), f2bf(v1), f2bf(v2), f2bf(v3) };
                    *(ushort4*)(Vt + ((size_t)b_ * 512 + c) * KROWS + nn) = pk;
                }
            }
        }
    } else {
        // EPI==3: rows = enc tokens (154), cols: [0,512)=Kenc, [512,1024)=Venc
        #pragma unroll
        for (int i = 0; i < 4; ++i) {
            int rg0 = m0 + wr * 64 + i * 16 + quad * 4;
            #pragma unroll
            for (int j = 0; j < 4; ++j) {
                int col = n0 + wc * 64 + j * 16 + l16;
                #pragma unroll
                for (int r = 0; r < 4; ++r) {
                    int rg = rg0 + r;
                    if (rg < 154) {
                        int b_ = rg >= 77;
                        int jj = rg - 77 * b_;
                        float v = acc[i][j][r] + bias[col];
                        if (col < 512)
                            Kcat[((size_t)b_ * KROWS + 1024 + jj) * 512 + col] = f2bf(v);
                        else
                            Vt[((size_t)b_ * 512 + (col - 512)) * KROWS + 1024 + jj] = f2bf(v);
                    }
                }
            }
        }
    }
}

// ---------------------------------------------------------------- MFMA flash attention
// Block = (b, h, qtile of 64). 4 waves x 16 queries. d=8 padded to K=32 (Q frag
// zeroed for quad!=0; K frags dup-loaded -> products vanish). Per 32-KV chunk:
// 2 S-MFMAs, per-wave online softmax (exp2 domain, Q pre-scaled), P->LDS->A-frag,
// 1 PV MFMA with Vt[ch][kv] B-frag. No block barriers (P tile is per-wave).
__global__ __launch_bounds__(256) void attn_mfma(
        const unsigned short* __restrict__ Qb,    // [2][1024][512]
        const unsigned short* __restrict__ Kcat,  // [2][KROWS][512]
        const unsigned short* __restrict__ Vt,    // [2][512][KROWS]
        unsigned short* __restrict__ AO) {        // [2][1024][512]
    __shared__ alignas(16) unsigned short P_lds[4][16][40];   // per-wave 16q x 32kv (+8 pad)
    int x = blockIdx.x;
    int h = x & 63, qt = (x >> 6) & 15, b = x >> 10;
    int tid = threadIdx.x, wv = tid >> 6, ln = tid & 63;
    int quad = ln >> 4, l16 = ln & 15;
    int qrow0 = qt * 64 + wv * 16;

    short8 qf = {};
    if (quad == 0)
        qf = *(const short8*)(Qb + ((size_t)(b * 1024 + qrow0 + l16)) * 512 + h * 8);

    const unsigned short* Kb = Kcat + (size_t)b * KROWS * 512 + h * 8;
    const unsigned short* Vb = Vt + ((size_t)b * 512 + h * 8 + (l16 & 7)) * KROWS;

    floatx4 m4, l4, acc;
    #pragma unroll
    for (int r = 0; r < 4; ++r) { m4[r] = -INFINITY; l4[r] = 0.f; acc[r] = 0.f; }

    unsigned short* Pw = &P_lds[wv][0][0];

    for (int base = 0; base < SKV; base += 32) {
        short8 k0 = *(const short8*)(Kb + (size_t)(base + l16) * 512);
        short8 k1 = *(const short8*)(Kb + (size_t)(base + 16 + l16) * 512);
        short8 vf = *(const short8*)(Vb + base + quad * 8);

        floatx4 s0 = {}, s1 = {};
        s0 = __builtin_amdgcn_mfma_f32_16x16x32_bf16(qf, k0, s0, 0, 0, 0);
        s1 = __builtin_amdgcn_mfma_f32_16x16x32_bf16(qf, k1, s1, 0, 0, 0);

        if (base + 32 > SKV) {                       // tail mask (last chunk only)
            bool v0 = (base + l16) < SKV;
            #pragma unroll
            for (int r = 0; r < 4; ++r) {
                s0[r] = v0 ? s0[r] : -INFINITY;
                s1[r] = -INFINITY;
            }
        }

        // wave-wide max (valid softmax reference; scores are O(1) so no underflow)
        float cm = fmaxf(fmaxf(fmaxf(s0[0], s0[1]), fmaxf(s0[2], s0[3])),
                         fmaxf(fmaxf(s1[0], s1[1]), fmaxf(s1[2], s1[3])));
        cm = fmaxf(cm, __shfl_xor(cm, 1));
        cm = fmaxf(cm, __shfl_xor(cm, 2));
        cm = fmaxf(cm, __shfl_xor(cm, 4));
        cm = fmaxf(cm, __shfl_xor(cm, 8));
        cm = fmaxf(cm, __shfl_xor(cm, 16));
        cm = fmaxf(cm, __shfl_xor(cm, 32));

        float mn = fmaxf(m4[0], cm);
        float corr = __builtin_amdgcn_exp2f(m4[0] - mn);
        #pragma unroll
        for (int r = 0; r < 4; ++r) m4[r] = mn;

        #pragma unroll
        for (int r = 0; r < 4; ++r) {
            float p0 = __builtin_amdgcn_exp2f(s0[r] - mn);
            float p1 = __builtin_amdgcn_exp2f(s1[r] - mn);
            l4[r] = l4[r] * corr + (p0 + p1);
            acc[r] *= corr;
            Pw[(quad * 4 + r) * 40 + l16]      = f2bf(p0);
            Pw[(quad * 4 + r) * 40 + 16 + l16] = f2bf(p1);
        }
        short8 pf = *(const short8*)(Pw + l16 * 40 + quad * 8);
        acc = __builtin_amdgcn_mfma_f32_16x16x32_bf16(pf, vf, acc, 0, 0, 0);
    }

    #pragma unroll
    for (int r = 0; r < 4; ++r) {
        float lv = l4[r];
        lv += __shfl_xor(lv, 1);
        lv += __shfl_xor(lv, 2);
        lv += __shfl_xor(lv, 4);
        lv += __shfl_xor(lv, 8);
        float inv = 1.f / lv;
        if (l16 < 8)
            AO[((size_t)(b * 1024 + qrow0 + quad * 4 + r)) * 512 + h * 8 + l16] =
                f2bf(acc[r] * inv);
    }
}

// ---------------------------------------------------------------- launcher
extern "C" void kernel_launch(void* const* d_in, const int* in_sizes, int n_in,
                              void* d_out, int out_size, void* d_ws, size_t ws_size,
                              hipStream_t stream) {
    const float* x    = (const float*)d_in[0];
    const float* enc  = (const float*)d_in[1];
    const float* gn_s = (const float*)d_in[2];
    const float* gn_b = (const float*)d_in[3];
    const float* ln_s = (const float*)d_in[4];
    const float* ln_b = (const float*)d_in[5];
    const float* Wq  = (const float*)d_in[6];   const float* bq  = (const float*)d_in[7];
    const float* Wk  = (const float*)d_in[8];   const float* bk  = (const float*)d_in[9];
    const float* Wv  = (const float*)d_in[10];  const float* bv  = (const float*)d_in[11];
    const float* Wak = (const float*)d_in[12];  const float* bak = (const float*)d_in[13];
    const float* Wav = (const float*)d_in[14];  const float* bav = (const float*)d_in[15];
    const float* Wo  = (const float*)d_in[16];  const float* bo  = (const float*)d_in[17];
    float* out = (float*)d_out;

    char* p = (char*)d_ws;
    auto alloc = [&](size_t bytes) { char* r = p; p += (bytes + 255) & ~255ULL; return r; };
    unsigned short* hs_bf  = (unsigned short*)alloc((size_t)2048 * 512 * 2);
    unsigned short* enc_bf = (unsigned short*)alloc((size_t)154 * 768 * 2);
    unsigned short* Wqkv_t = (unsigned short*)alloc((size_t)1536 * 512 * 2);
    unsigned short* Wakv_t = (unsigned short*)alloc((size_t)1024 * 768 * 2);
    unsigned short* Wo_t   = (unsigned short*)alloc((size_t)512 * 512 * 2);
    float* bqkv = (float*)alloc(1536 * 4);
    float* bakv = (float*)alloc(1024 * 4);
    unsigned short* Qb   = (unsigned short*)alloc((size_t)2 * 1024 * 512 * 2);
    unsigned short* Kcat = (unsigned short*)alloc((size_t)2 * KROWS * 512 * 2);
    unsigned short* Vt   = (unsigned short*)alloc((size_t)2 * 512 * KROWS * 2);
    unsigned short* AO   = (unsigned short*)alloc((size_t)2048 * 512 * 2);

    prep_all<<<2020, 256, 0, stream>>>(
        Wq, Wk, Wv, Wak, Wav, Wo, bq, bk, bv, bak, bav,
        enc, ln_s, ln_b, x, gn_s, gn_b,
        Wqkv_t, Wakv_t, Wo_t, bqkv, bakv, enc_bf, hs_bf);

    // QKV: [2048,512] x [512,1536] -> Qb/Kcat/Vt
    mfma_gemm<2><<<dim3(12, 16), 256, 0, stream>>>(
        hs_bf, 2048, Wqkv_t, bqkv, 512, Qb, Kcat, Vt, nullptr, nullptr);
    // enc K/V: [154,768] x [768,1024] -> Kcat/Vt (rows 1024+)
    mfma_gemm<3><<<dim3(8, 2), 256, 0, stream>>>(
        enc_bf, 154, Wakv_t, bakv, 768, nullptr, Kcat, Vt, nullptr, nullptr);

    attn_mfma<<<2048, 256, 0, stream>>>(Qb, Kcat, Vt, AO);

    // out-proj as C^T: A=Wo_t [512,512], Bt=AO [2048,512] -> out [B,C,N] + bias + residual
    mfma_gemm<1><<<dim3(16, 4), 256, 0, stream>>>(
        Wo_t, 512, AO, bo, 512, nullptr, nullptr, nullptr, out, x);

    (void)in_sizes; (void)n_in; (void)out_size; (void)ws_size;
}

// Round 6
// 221.572 us; speedup vs baseline: 1.6751x; 1.1961x over previous
//
#include <hip/hip_runtime.h>
#include <math.h>

// Problem constants
#define BSZ   2
#define NTOK  1024          // 32*32
#define CDIM  512
#define SENC  77
#define SKV   1101          // 77 + 1024 (order: self rows 0..1023, enc rows 1024..1100)
#define KROWS 1120          // padded KV rows (35 chunks of 32)
#define ENCD  768
#define NHEAD 64
#define DHEAD 8

typedef short short8 __attribute__((ext_vector_type(8)));
typedef float floatx4 __attribute__((ext_vector_type(4)));

__device__ __forceinline__ unsigned short f2bf(float f) {
    union { float f; unsigned int u; } v; v.f = f;
    unsigned int r = v.u + 0x7FFF + ((v.u >> 16) & 1);   // RNE
    return (unsigned short)(r >> 16);
}

// C-style casts: clang only allows addrspacecast via C-style
__device__ __forceinline__ void gld16(const void* g, void* l) {
    __builtin_amdgcn_global_load_lds(
        (const __attribute__((address_space(1))) unsigned int*)g,
        (__attribute__((address_space(3))) unsigned int*)l,
        16, 0, 0);
}

// ---------------------------------------------------------------- reductions
__device__ __forceinline__ float block_reduce_sum(float v) {
    #pragma unroll
    for (int off = 32; off > 0; off >>= 1) v += __shfl_down(v, off, 64);
    __shared__ float tmp[4];
    int lane = threadIdx.x & 63, wid = threadIdx.x >> 6;
    if (lane == 0) tmp[wid] = v;
    __syncthreads();
    if (wid == 0) {
        float r = (lane < 4) ? tmp[lane] : 0.f;
        r += __shfl_down(r, 2, 64);
        r += __shfl_down(r, 1, 64);
        if (lane == 0) tmp[0] = r;
    }
    __syncthreads();
    float out = tmp[0];
    __syncthreads();
    return out;
}

// ---------------------------------------------------------------- prep device parts
__device__ void layernorm_dev(int row, const float* __restrict__ x,
                              const float* __restrict__ sc, const float* __restrict__ bi,
                              unsigned short* __restrict__ out) {
    const float* xp = x + (size_t)row * ENCD;
    unsigned short* op = out + (size_t)row * ENCD;
    int t = threadIdx.x;
    float v0 = xp[t], v1 = xp[t + 256], v2 = xp[t + 512];
    float mu = block_reduce_sum(v0 + v1 + v2) * (1.f / ENCD);
    float d0 = v0 - mu, d1 = v1 - mu, d2 = v2 - mu;
    float var = block_reduce_sum(d0 * d0 + d1 * d1 + d2 * d2) * (1.f / ENCD);
    float rstd = rsqrtf(var + 1e-5f);
    op[t]       = f2bf(d0 * rstd * sc[t]       + bi[t]);
    op[t + 256] = f2bf(d1 * rstd * sc[t + 256] + bi[t + 256]);
    op[t + 512] = f2bf(d2 * rstd * sc[t + 512] + bi[t + 512]);
}

__device__ void groupnorm_dev(int bg, const float* __restrict__ x,
                              const float* __restrict__ sc, const float* __restrict__ bi,
                              unsigned short* __restrict__ out) {
    int b = bg >> 5, g = bg & 31;
    const float* xp = x + (size_t)b * NTOK * CDIM + g * 16;
    unsigned short* op = out + (size_t)b * NTOK * CDIM + g * 16;
    int t = threadIdx.x;

    float s = 0.f;
    for (int idx = t; idx < 4096; idx += 256) {
        int n = idx >> 2, q = idx & 3;
        float4 v = *(const float4*)(xp + n * CDIM + q * 4);
        s += (v.x + v.y) + (v.z + v.w);
    }
    float mu = block_reduce_sum(s) * (1.f / 16384.f);

    float vs = 0.f;
    for (int idx = t; idx < 4096; idx += 256) {
        int n = idx >> 2, q = idx & 3;
        float4 v = *(const float4*)(xp + n * CDIM + q * 4);
        float dx = v.x - mu, dy = v.y - mu, dz = v.z - mu, dw = v.w - mu;
        vs += (dx * dx + dy * dy) + (dz * dz + dw * dw);
    }
    float var = block_reduce_sum(vs) * (1.f / 16384.f);
    float rstd = rsqrtf(var + 1e-5f);

    for (int idx = t; idx < 4096; idx += 256) {
        int n = idx >> 2, q = idx & 3;
        float4 v = *(const float4*)(xp + n * CDIM + q * 4);
        float4 s4 = *(const float4*)(sc + g * 16 + q * 4);
        float4 b4 = *(const float4*)(bi + g * 16 + q * 4);
        ushort4 o;
        o.x = f2bf((v.x - mu) * rstd * s4.x + b4.x);
        o.y = f2bf((v.y - mu) * rstd * s4.y + b4.y);
        o.z = f2bf((v.z - mu) * rstd * s4.z + b4.z);
        o.w = f2bf((v.w - mu) * rstd * s4.w + b4.w);
        *(ushort4*)(op + n * CDIM + q * 4) = o;
    }
}

// transpose+cast one 32x32 tile: W[K][N] fp32 -> Wt[N+roff][K] bf16
__device__ void tcast_dev(const float* __restrict__ W, unsigned short* __restrict__ Wt,
                          int K, int N, int roff, int local) {
    __shared__ float t[32][33];
    int bn = (local & 15) * 32, bk = (local >> 4) * 32;
    int lx = threadIdx.x & 31, ly = threadIdx.x >> 5;
    #pragma unroll
    for (int r = 0; r < 4; ++r)
        t[ly + 8 * r][lx] = W[(size_t)(bk + ly + 8 * r) * N + bn + lx];
    __syncthreads();
    #pragma unroll
    for (int r = 0; r < 4; ++r)
        Wt[(size_t)(roff + bn + ly + 8 * r) * K + bk + lx] = f2bf(t[lx][ly + 8 * r]);
}

// ---------------------------------------------------------------- fused preprocessing
__global__ __launch_bounds__(256) void prep_all(
        const float* __restrict__ Wq, const float* __restrict__ Wk, const float* __restrict__ Wv,
        const float* __restrict__ Wak, const float* __restrict__ Wav, const float* __restrict__ Wo,
        const float* __restrict__ bq, const float* __restrict__ bk, const float* __restrict__ bv,
        const float* __restrict__ bak, const float* __restrict__ bav,
        const float* __restrict__ enc, const float* __restrict__ ln_s, const float* __restrict__ ln_b,
        const float* __restrict__ x, const float* __restrict__ gn_s, const float* __restrict__ gn_b,
        unsigned short* __restrict__ Wqkv_t, unsigned short* __restrict__ Wakv_t,
        unsigned short* __restrict__ Wo_t,
        float* __restrict__ bqkv, float* __restrict__ bakv,
        unsigned short* __restrict__ enc_bf, unsigned short* __restrict__ hs_bf,
        unsigned short* __restrict__ Vh) {
    int bid = blockIdx.x;
    if (bid < 256)        tcast_dev(Wq,  Wqkv_t, 512, 512, 0,    bid);
    else if (bid < 512)   tcast_dev(Wk,  Wqkv_t, 512, 512, 512,  bid - 256);
    else if (bid < 768)   tcast_dev(Wv,  Wqkv_t, 512, 512, 1024, bid - 512);
    else if (bid < 1152)  tcast_dev(Wak, Wakv_t, 768, 512, 0,    bid - 768);
    else if (bid < 1536)  tcast_dev(Wav, Wakv_t, 768, 512, 512,  bid - 1152);
    else if (bid < 1792)  tcast_dev(Wo,  Wo_t,   512, 512, 0,    bid - 1536);
    else if (bid < 1802) {
        int i = (bid - 1792) * 256 + threadIdx.x;
        if (i < 512)        bqkv[i] = bq[i];
        else if (i < 1024)  bqkv[i] = bk[i - 512];
        else if (i < 1536)  bqkv[i] = bv[i - 1024];
        else if (i < 2048)  bakv[i - 1536] = bak[i - 1536];
        else if (i < 2560)  bakv[i - 1536] = bav[i - 2048];
    }
    else if (bid < 1956)  layernorm_dev(bid - 1802, enc, ln_s, ln_b, enc_bf);
    else if (bid < 2020)  groupnorm_dev(bid - 1956, x, gn_s, gn_b, hs_bf);
    else {
        // ones-row (ch=8) of Vh for the l=sum(p) trick: 2*64*1120 = 143360 elems
        int i = (bid - 2020) * 256 + threadIdx.x;   // [0, 143360)
        int g = i / KROWS, kv = i - g * KROWS;      // g = b*64+h
        Vh[((size_t)g * 16 + 8) * KROWS + kv] = 0x3F80;  // bf16 1.0
    }
}

// ---------------------------------------------------------------- bf16 MFMA GEMM
// D[M,N] = A[M,K](bf16) @ Bt[N,K](bf16)^T + bias.  128x128 block, 4 waves 2x2.
// EPI=1: out-proj: out[(b*512+row)*1024+n] = acc + bias[row] + resid  (fp32)
// EPI=2: QKV epilogue -> head-major Qh/Kh/Vh
// EPI=3: enc KV epilogue -> Kh/Vh rows 1024+
template <int EPI>
__global__ __launch_bounds__(256) void mfma_gemm(
        const unsigned short* __restrict__ A, int Mv,
        const unsigned short* __restrict__ Bt,
        const float* __restrict__ bias, int K,
        unsigned short* __restrict__ Qh, unsigned short* __restrict__ Kh,
        unsigned short* __restrict__ Vh,
        float* __restrict__ out, const float* __restrict__ resid) {
    __shared__ alignas(16) unsigned short AsS[128 * 32];
    __shared__ alignas(16) unsigned short BsS[128 * 32];
    int tid = threadIdx.x;
    int wv = tid >> 6, ln = tid & 63;
    int quad = ln >> 4, l16 = ln & 15;
    int wr = wv >> 1, wc = wv & 1;
    int n0 = blockIdx.x * 128, m0 = blockIdx.y * 128;

    floatx4 acc[4][4] = {};

    for (int k0 = 0; k0 < K; k0 += 32) {
        #pragma unroll
        for (int it = 0; it < 2; ++it) {
            int cb = it * 256 + wv * 64;
            int c = cb + ln;
            int r = c >> 2, sg = c & 3;
            int row = m0 + r; if (row > Mv - 1) row = Mv - 1;
            const unsigned short* ga = A + (size_t)row * K + k0 + sg * 8;
            gld16((const void*)ga, (void*)((char*)AsS + cb * 16));
            const unsigned short* gb = Bt + (size_t)(n0 + r) * K + k0 + sg * 8;
            gld16((const void*)gb, (void*)((char*)BsS + cb * 16));
        }
        __syncthreads();
        short8 af[4], bf[4];
        #pragma unroll
        for (int i = 0; i < 4; ++i)
            af[i] = *(const short8*)(AsS + (wr * 64 + i * 16 + l16) * 32 + quad * 8);
        #pragma unroll
        for (int j = 0; j < 4; ++j)
            bf[j] = *(const short8*)(BsS + (wc * 64 + j * 16 + l16) * 32 + quad * 8);
        #pragma unroll
        for (int i = 0; i < 4; ++i)
            #pragma unroll
            for (int j = 0; j < 4; ++j)
                acc[i][j] = __builtin_amdgcn_mfma_f32_16x16x32_bf16(af[i], bf[j], acc[i][j], 0, 0, 0);
        __syncthreads();
    }

    const float ASCALE = 0.3535533905932738f * 1.4426950408889634f;  // 1/sqrt(8)*log2(e)

    if (EPI == 1) {
        // rows are channels c (Mv=512), cols are global tokens n_g (N=2048)
        #pragma unroll
        for (int i = 0; i < 4; ++i) {
            int cbase = m0 + wr * 64 + i * 16 + quad * 4;
            #pragma unroll
            for (int j = 0; j < 4; ++j) {
                int ng = n0 + wc * 64 + j * 16 + l16;
                int b = ng >> 10, n = ng & 1023;
                float4 res = *(const float4*)(resid + ((size_t)(b * 1024 + n)) * 512 + cbase);
                float rr[4] = {res.x, res.y, res.z, res.w};
                #pragma unroll
                for (int r = 0; r < 4; ++r) {
                    int c = cbase + r;
                    out[((size_t)(b * 512 + c)) * 1024 + n] = acc[i][j][r] + bias[c] + rr[r];
                }
            }
        }
    } else if (EPI == 2) {
        // rows = tokens (2048), cols: [0,512)=Q, [512,1024)=K, [1024,1536)=V
        #pragma unroll
        for (int i = 0; i < 4; ++i) {
            int t0 = m0 + wr * 64 + i * 16 + quad * 4;   // 4 consecutive tokens
            int b_ = t0 >> 10, nn = t0 & 1023;
            #pragma unroll
            for (int j = 0; j < 4; ++j) {
                int col = n0 + wc * 64 + j * 16 + l16;
                float v0 = acc[i][j][0] + bias[col];
                float v1 = acc[i][j][1] + bias[col];
                float v2 = acc[i][j][2] + bias[col];
                float v3 = acc[i][j][3] + bias[col];
                if (col < 512) {
                    int h = col >> 3, c = col & 7;
                    unsigned short* qp = Qh + (((size_t)b_ * 64 + h) * 1024 + nn) * 8 + c;
                    qp[0]  = f2bf(v0 * ASCALE);
                    qp[8]  = f2bf(v1 * ASCALE);
                    qp[16] = f2bf(v2 * ASCALE);
                    qp[24] = f2bf(v3 * ASCALE);
                } else if (col < 1024) {
                    int cc = col - 512, h = cc >> 3, c = cc & 7;
                    unsigned short* kp = Kh + (((size_t)b_ * 64 + h) * KROWS + nn) * 8 + c;
                    kp[0]  = f2bf(v0);
                    kp[8]  = f2bf(v1);
                    kp[16] = f2bf(v2);
                    kp[24] = f2bf(v3);
                } else {
                    int cc = col - 1024, h = cc >> 3, c = cc & 7;
                    ushort4 pk = { f2bf(v0), f2bf(v1), f2bf(v2), f2bf(v3) };
                    *(ushort4*)(Vh + (((size_t)b_ * 64 + h) * 16 + c) * KROWS + nn) = pk;
                }
            }
        }
    } else {
        // EPI==3: rows = enc tokens (154), cols: [0,512)=Kenc, [512,1024)=Venc
        #pragma unroll
        for (int i = 0; i < 4; ++i) {
            int rg0 = m0 + wr * 64 + i * 16 + quad * 4;
            #pragma unroll
            for (int j = 0; j < 4; ++j) {
                int col = n0 + wc * 64 + j * 16 + l16;
                #pragma unroll
                for (int r = 0; r < 4; ++r) {
                    int rg = rg0 + r;
                    if (rg < 154) {
                        int b_ = rg >= 77;
                        int jj = rg - 77 * b_;
                        float v = acc[i][j][r] + bias[col];
                        if (col < 512) {
                            int h = col >> 3, c = col & 7;
                            Kh[(((size_t)b_ * 64 + h) * KROWS + 1024 + jj) * 8 + c] = f2bf(v);
                        } else {
                            int cc = col - 512, h = cc >> 3, c = cc & 7;
                            Vh[(((size_t)b_ * 64 + h) * 16 + c) * KROWS + 1024 + jj] = f2bf(v);
                        }
                    }
                }
            }
        }
    }
}

// ---------------------------------------------------------------- MFMA flash attention
// Block = (b, h, qtile of 64); 4 waves x 16 queries. Fixed-max softmax (m=0,
// exact: scores pre-scaled into exp2 domain are O(1)). l = sum(p) computed by
// the PV MFMA via ones-row at V ch=8. P: RTZ bf16 through per-wave LDS tile.
// K loads: 256 B contiguous wave-broadcast (head-major layout). No barriers.
__global__ __launch_bounds__(256) void attn_mfma(
        const unsigned short* __restrict__ Qh,   // [2][64][1024][8]
        const unsigned short* __restrict__ Kh,   // [2][64][KROWS][8]
        const unsigned short* __restrict__ Vh,   // [2][64][16][KROWS]
        unsigned short* __restrict__ AO) {       // [2048][512]
    __shared__ alignas(16) unsigned short P_lds[4][16][40];
    int x = blockIdx.x;
    int h = x & 63, qt = (x >> 6) & 15, b = x >> 10;
    int tid = threadIdx.x, wv = tid >> 6, ln = tid & 63;
    int quad = ln >> 4, l16 = ln & 15;
    int qrow0 = qt * 64 + wv * 16;
    int bh = b * 64 + h;

    short8 qf = {};
    if (quad == 0)
        qf = *(const short8*)(Qh + ((size_t)bh * 1024 + qrow0 + l16) * 8);

    const unsigned short* Kb = Kh + (size_t)bh * KROWS * 8;
    const unsigned short* Vb = Vh + ((size_t)bh * 16 + l16) * KROWS;

    floatx4 acc = {};
    unsigned short* Pw = &P_lds[wv][0][0];

    for (int base = 0; base < 1088; base += 32) {        // kv 0..1087 all valid
        short8 k0 = *(const short8*)(Kb + (size_t)(base + l16) * 8);
        short8 k1 = *(const short8*)(Kb + (size_t)(base + 16 + l16) * 8);
        short8 vf = *(const short8*)(Vb + base + quad * 8);
        floatx4 s0 = {}, s1 = {};
        s0 = __builtin_amdgcn_mfma_f32_16x16x32_bf16(qf, k0, s0, 0, 0, 0);
        s1 = __builtin_amdgcn_mfma_f32_16x16x32_bf16(qf, k1, s1, 0, 0, 0);
        #pragma unroll
        for (int r = 0; r < 4; ++r) {
            float p0 = __builtin_amdgcn_exp2f(s0[r]);
            float p1 = __builtin_amdgcn_exp2f(s1[r]);
            Pw[(quad * 4 + r) * 40 + l16]      = (unsigned short)(__float_as_uint(p0) >> 16);
            Pw[(quad * 4 + r) * 40 + 16 + l16] = (unsigned short)(__float_as_uint(p1) >> 16);
        }
        short8 pf = *(const short8*)(Pw + l16 * 40 + quad * 8);
        acc = __builtin_amdgcn_mfma_f32_16x16x32_bf16(pf, vf, acc, 0, 0, 0);
    }
    {   // tail chunk base=1088: valid kv 1088..1100 (13 of 32)
        short8 k0 = *(const short8*)(Kb + (size_t)(1088 + l16) * 8);
        short8 vf = *(const short8*)(Vb + 1088 + quad * 8);
        floatx4 s0 = {};
        s0 = __builtin_amdgcn_mfma_f32_16x16x32_bf16(qf, k0, s0, 0, 0, 0);
        #pragma unroll
        for (int r = 0; r < 4; ++r) {
            float p0 = (l16 < 13) ? __builtin_amdgcn_exp2f(s0[r]) : 0.f;
            Pw[(quad * 4 + r) * 40 + l16]      = (unsigned short)(__float_as_uint(p0) >> 16);
            Pw[(quad * 4 + r) * 40 + 16 + l16] = 0;
        }
        short8 pf = *(const short8*)(Pw + l16 * 40 + quad * 8);
        acc = __builtin_amdgcn_mfma_f32_16x16x32_bf16(pf, vf, acc, 0, 0, 0);
    }

    #pragma unroll
    for (int r = 0; r < 4; ++r) {
        float lv = __shfl(acc[r], (ln & 48) + 8, 64);    // l from ones-column (ch=8)
        if (l16 < 8)
            AO[((size_t)(b * 1024 + qrow0 + quad * 4 + r)) * 512 + h * 8 + l16] =
                f2bf(acc[r] / lv);
    }
}

// ---------------------------------------------------------------- launcher
extern "C" void kernel_launch(void* const* d_in, const int* in_sizes, int n_in,
                              void* d_out, int out_size, void* d_ws, size_t ws_size,
                              hipStream_t stream) {
    const float* x    = (const float*)d_in[0];
    const float* enc  = (const float*)d_in[1];
    const float* gn_s = (const float*)d_in[2];
    const float* gn_b = (const float*)d_in[3];
    const float* ln_s = (const float*)d_in[4];
    const float* ln_b = (const float*)d_in[5];
    const float* Wq  = (const float*)d_in[6];   const float* bq  = (const float*)d_in[7];
    const float* Wk  = (const float*)d_in[8];   const float* bk  = (const float*)d_in[9];
    const float* Wv  = (const float*)d_in[10];  const float* bv  = (const float*)d_in[11];
    const float* Wak = (const float*)d_in[12];  const float* bak = (const float*)d_in[13];
    const float* Wav = (const float*)d_in[14];  const float* bav = (const float*)d_in[15];
    const float* Wo  = (const float*)d_in[16];  const float* bo  = (const float*)d_in[17];
    float* out = (float*)d_out;

    char* p = (char*)d_ws;
    auto alloc = [&](size_t bytes) { char* r = p; p += (bytes + 255) & ~255ULL; return r; };
    unsigned short* hs_bf  = (unsigned short*)alloc((size_t)2048 * 512 * 2);
    unsigned short* enc_bf = (unsigned short*)alloc((size_t)154 * 768 * 2);
    unsigned short* Wqkv_t = (unsigned short*)alloc((size_t)1536 * 512 * 2);
    unsigned short* Wakv_t = (unsigned short*)alloc((size_t)1024 * 768 * 2);
    unsigned short* Wo_t   = (unsigned short*)alloc((size_t)512 * 512 * 2);
    float* bqkv = (float*)alloc(1536 * 4);
    float* bakv = (float*)alloc(1024 * 4);
    unsigned short* Qh = (unsigned short*)alloc((size_t)2 * 64 * 1024 * 8 * 2);
    unsigned short* Kh = (unsigned short*)alloc((size_t)2 * 64 * KROWS * 8 * 2);
    unsigned short* Vh = (unsigned short*)alloc((size_t)2 * 64 * 16 * KROWS * 2);
    unsigned short* AO = (unsigned short*)alloc((size_t)2048 * 512 * 2);

    prep_all<<<2580, 256, 0, stream>>>(
        Wq, Wk, Wv, Wak, Wav, Wo, bq, bk, bv, bak, bav,
        enc, ln_s, ln_b, x, gn_s, gn_b,
        Wqkv_t, Wakv_t, Wo_t, bqkv, bakv, enc_bf, hs_bf, Vh);

    // QKV: [2048,512] x [512,1536] -> Qh/Kh/Vh (head-major)
    mfma_gemm<2><<<dim3(12, 16), 256, 0, stream>>>(
        hs_bf, 2048, Wqkv_t, bqkv, 512, Qh, Kh, Vh, nullptr, nullptr);
    // enc K/V: [154,768] x [768,1024] -> Kh/Vh rows 1024+
    mfma_gemm<3><<<dim3(8, 2), 256, 0, stream>>>(
        enc_bf, 154, Wakv_t, bakv, 768, nullptr, Kh, Vh, nullptr, nullptr);

    attn_mfma<<<2048, 256, 0, stream>>>(Qh, Kh, Vh, AO);

    // out-proj as C^T: A=Wo_t [512,512], Bt=AO [2048,512] -> out [B,C,N] + bias + residual
    mfma_gemm<1><<<dim3(16, 4), 256, 0, stream>>>(
        Wo_t, 512, AO, bo, 512, nullptr, nullptr, nullptr, out, x);

    (void)in_sizes; (void)n_in; (void)out_size; (void)ws_size;
}

// Round 7
// 181.907 us; speedup vs baseline: 2.0404x; 1.2181x over previous
//
#include <hip/hip_runtime.h>
#include <math.h>

// Problem constants
#define BSZ   2
#define NTOK  1024          // 32*32
#define CDIM  512
#define SENC  77
#define SKV   1101          // 77 + 1024 (order: self rows 0..1023, enc rows 1024..1100)
#define KROWS 1120          // padded KV rows (35 chunks of 32)
#define ENCD  768
#define NHEAD 64
#define DHEAD 8

typedef short short8 __attribute__((ext_vector_type(8)));
typedef float floatx4 __attribute__((ext_vector_type(4)));
typedef unsigned short ushortx4 __attribute__((ext_vector_type(4)));

__device__ __forceinline__ unsigned short f2bf(float f) {
    union { float f; unsigned int u; } v; v.f = f;
    unsigned int r = v.u + 0x7FFF + ((v.u >> 16) & 1);   // RNE
    return (unsigned short)(r >> 16);
}
__device__ __forceinline__ unsigned short rtzbf(float f) {
    return (unsigned short)(__float_as_uint(f) >> 16);   // RTZ (cancels in softmax norm)
}

// C-style casts: clang only allows addrspacecast via C-style
__device__ __forceinline__ void gld16(const void* g, void* l) {
    __builtin_amdgcn_global_load_lds(
        (const __attribute__((address_space(1))) unsigned int*)g,
        (__attribute__((address_space(3))) unsigned int*)l,
        16, 0, 0);
}

// ---------------------------------------------------------------- reductions
__device__ __forceinline__ float block_reduce_sum(float v) {
    #pragma unroll
    for (int off = 32; off > 0; off >>= 1) v += __shfl_down(v, off, 64);
    __shared__ float tmp[4];
    int lane = threadIdx.x & 63, wid = threadIdx.x >> 6;
    if (lane == 0) tmp[wid] = v;
    __syncthreads();
    if (wid == 0) {
        float r = (lane < 4) ? tmp[lane] : 0.f;
        r += __shfl_down(r, 2, 64);
        r += __shfl_down(r, 1, 64);
        if (lane == 0) tmp[0] = r;
    }
    __syncthreads();
    float out = tmp[0];
    __syncthreads();
    return out;
}

// ---------------------------------------------------------------- prep device parts
__device__ void layernorm_dev(int row, const float* __restrict__ x,
                              const float* __restrict__ sc, const float* __restrict__ bi,
                              unsigned short* __restrict__ out) {
    const float* xp = x + (size_t)row * ENCD;
    unsigned short* op = out + (size_t)row * ENCD;
    int t = threadIdx.x;
    float v0 = xp[t], v1 = xp[t + 256], v2 = xp[t + 512];
    float mu = block_reduce_sum(v0 + v1 + v2) * (1.f / ENCD);
    float d0 = v0 - mu, d1 = v1 - mu, d2 = v2 - mu;
    float var = block_reduce_sum(d0 * d0 + d1 * d1 + d2 * d2) * (1.f / ENCD);
    float rstd = rsqrtf(var + 1e-5f);
    op[t]       = f2bf(d0 * rstd * sc[t]       + bi[t]);
    op[t + 256] = f2bf(d1 * rstd * sc[t + 256] + bi[t + 256]);
    op[t + 512] = f2bf(d2 * rstd * sc[t + 512] + bi[t + 512]);
}

__device__ void groupnorm_dev(int bg, const float* __restrict__ x,
                              const float* __restrict__ sc, const float* __restrict__ bi,
                              unsigned short* __restrict__ out) {
    int b = bg >> 5, g = bg & 31;
    const float* xp = x + (size_t)b * NTOK * CDIM + g * 16;
    unsigned short* op = out + (size_t)b * NTOK * CDIM + g * 16;
    int t = threadIdx.x;

    float s = 0.f;
    for (int idx = t; idx < 4096; idx += 256) {
        int n = idx >> 2, q = idx & 3;
        float4 v = *(const float4*)(xp + n * CDIM + q * 4);
        s += (v.x + v.y) + (v.z + v.w);
    }
    float mu = block_reduce_sum(s) * (1.f / 16384.f);

    float vs = 0.f;
    for (int idx = t; idx < 4096; idx += 256) {
        int n = idx >> 2, q = idx & 3;
        float4 v = *(const float4*)(xp + n * CDIM + q * 4);
        float dx = v.x - mu, dy = v.y - mu, dz = v.z - mu, dw = v.w - mu;
        vs += (dx * dx + dy * dy) + (dz * dz + dw * dw);
    }
    float var = block_reduce_sum(vs) * (1.f / 16384.f);
    float rstd = rsqrtf(var + 1e-5f);

    for (int idx = t; idx < 4096; idx += 256) {
        int n = idx >> 2, q = idx & 3;
        float4 v = *(const float4*)(xp + n * CDIM + q * 4);
        float4 s4 = *(const float4*)(sc + g * 16 + q * 4);
        float4 b4 = *(const float4*)(bi + g * 16 + q * 4);
        ushort4 o;
        o.x = f2bf((v.x - mu) * rstd * s4.x + b4.x);
        o.y = f2bf((v.y - mu) * rstd * s4.y + b4.y);
        o.z = f2bf((v.z - mu) * rstd * s4.z + b4.z);
        o.w = f2bf((v.w - mu) * rstd * s4.w + b4.w);
        *(ushort4*)(op + n * CDIM + q * 4) = o;
    }
}

// transpose+cast one 32x32 tile: W[K][N] fp32 -> Wt[N+roff][K] bf16
__device__ void tcast_dev(const float* __restrict__ W, unsigned short* __restrict__ Wt,
                          int K, int N, int roff, int local) {
    __shared__ float t[32][33];
    int bn = (local & 15) * 32, bk = (local >> 4) * 32;
    int lx = threadIdx.x & 31, ly = threadIdx.x >> 5;
    #pragma unroll
    for (int r = 0; r < 4; ++r)
        t[ly + 8 * r][lx] = W[(size_t)(bk + ly + 8 * r) * N + bn + lx];
    __syncthreads();
    #pragma unroll
    for (int r = 0; r < 4; ++r)
        Wt[(size_t)(roff + bn + ly + 8 * r) * K + bk + lx] = f2bf(t[lx][ly + 8 * r]);
}

// ---------------------------------------------------------------- fused preprocessing
__global__ __launch_bounds__(256) void prep_all(
        const float* __restrict__ Wq, const float* __restrict__ Wk, const float* __restrict__ Wv,
        const float* __restrict__ Wak, const float* __restrict__ Wav, const float* __restrict__ Wo,
        const float* __restrict__ bq, const float* __restrict__ bk, const float* __restrict__ bv,
        const float* __restrict__ bak, const float* __restrict__ bav,
        const float* __restrict__ enc, const float* __restrict__ ln_s, const float* __restrict__ ln_b,
        const float* __restrict__ x, const float* __restrict__ gn_s, const float* __restrict__ gn_b,
        unsigned short* __restrict__ Wqkv_t, unsigned short* __restrict__ Wakv_t,
        unsigned short* __restrict__ Wo_t,
        float* __restrict__ bqkv, float* __restrict__ bakv,
        unsigned short* __restrict__ enc_bf, unsigned short* __restrict__ hs_bf,
        unsigned short* __restrict__ Vh) {
    int bid = blockIdx.x;
    if (bid < 256)        tcast_dev(Wq,  Wqkv_t, 512, 512, 0,    bid);
    else if (bid < 512)   tcast_dev(Wk,  Wqkv_t, 512, 512, 512,  bid - 256);
    else if (bid < 768)   tcast_dev(Wv,  Wqkv_t, 512, 512, 1024, bid - 512);
    else if (bid < 1152)  tcast_dev(Wak, Wakv_t, 768, 512, 0,    bid - 768);
    else if (bid < 1536)  tcast_dev(Wav, Wakv_t, 768, 512, 512,  bid - 1152);
    else if (bid < 1792)  tcast_dev(Wo,  Wo_t,   512, 512, 0,    bid - 1536);
    else if (bid < 1802) {
        int i = (bid - 1792) * 256 + threadIdx.x;
        if (i < 512)        bqkv[i] = bq[i];
        else if (i < 1024)  bqkv[i] = bk[i - 512];
        else if (i < 1536)  bqkv[i] = bv[i - 1024];
        else if (i < 2048)  bakv[i - 1536] = bak[i - 1536];
        else if (i < 2560)  bakv[i - 1536] = bav[i - 2048];
    }
    else if (bid < 1956)  layernorm_dev(bid - 1802, enc, ln_s, ln_b, enc_bf);
    else if (bid < 2020)  groupnorm_dev(bid - 1956, x, gn_s, gn_b, hs_bf);
    else {
        // ones-row (ch=8) of Vh for the l=sum(p) trick: 2*64*1120 = 143360 elems
        int i = (bid - 2020) * 256 + threadIdx.x;   // [0, 143360)
        int g = i / KROWS, kv = i - g * KROWS;      // g = b*64+h
        Vh[((size_t)g * 16 + 8) * KROWS + kv] = 0x3F80;  // bf16 1.0
    }
}

// ---------------------------------------------------------------- shared GEMM core
// 128x128 tile, 4 waves 2x2, 16x16x32 bf16 MFMA, global_load_lds staging.
__device__ __forceinline__ void gemm_core(
        const unsigned short* __restrict__ A, int Mv,
        const unsigned short* __restrict__ Bt, int K,
        int m0, int n0, unsigned short* AsS, unsigned short* BsS,
        floatx4 (&acc)[4][4]) {
    int tid = threadIdx.x;
    int wv = tid >> 6, ln = tid & 63;
    int quad = ln >> 4, l16 = ln & 15;
    int wr = wv >> 1, wc = wv & 1;

    for (int k0 = 0; k0 < K; k0 += 32) {
        #pragma unroll
        for (int it = 0; it < 2; ++it) {
            int cb = it * 256 + wv * 64;
            int c = cb + ln;
            int r = c >> 2, sg = c & 3;
            int row = m0 + r; if (row > Mv - 1) row = Mv - 1;
            gld16((const void*)(A + (size_t)row * K + k0 + sg * 8),
                  (void*)((char*)AsS + cb * 16));
            gld16((const void*)(Bt + (size_t)(n0 + r) * K + k0 + sg * 8),
                  (void*)((char*)BsS + cb * 16));
        }
        __syncthreads();
        short8 af[4], bf[4];
        #pragma unroll
        for (int i = 0; i < 4; ++i)
            af[i] = *(const short8*)(AsS + (wr * 64 + i * 16 + l16) * 32 + quad * 8);
        #pragma unroll
        for (int j = 0; j < 4; ++j)
            bf[j] = *(const short8*)(BsS + (wc * 64 + j * 16 + l16) * 32 + quad * 8);
        #pragma unroll
        for (int i = 0; i < 4; ++i)
            #pragma unroll
            for (int j = 0; j < 4; ++j)
                acc[i][j] = __builtin_amdgcn_mfma_f32_16x16x32_bf16(af[i], bf[j], acc[i][j], 0, 0, 0);
        __syncthreads();
    }
}

// ---------------------------------------------------------------- merged projections
// blocks [0,192): QKV [2048,512]x[512,1536] -> head-major Qh/Kh/Vh
// blocks [192,208): enc KV [154,768]x[768,1024] -> Kh/Vh rows 1024+
__global__ __launch_bounds__(256) void proj_gemm(
        const unsigned short* __restrict__ hs_bf, const unsigned short* __restrict__ enc_bf,
        const unsigned short* __restrict__ Wqkv_t, const unsigned short* __restrict__ Wakv_t,
        const float* __restrict__ bqkv, const float* __restrict__ bakv,
        unsigned short* __restrict__ Qh, unsigned short* __restrict__ Kh,
        unsigned short* __restrict__ Vh) {
    __shared__ alignas(16) unsigned short AsS[128 * 32];
    __shared__ alignas(16) unsigned short BsS[128 * 32];
    floatx4 acc[4][4] = {};
    int bid = blockIdx.x;
    int tid = threadIdx.x;
    int wv = tid >> 6, ln = tid & 63;
    int quad = ln >> 4, l16 = ln & 15;
    int wr = wv >> 1, wc = wv & 1;
    const float ASCALE = 0.3535533905932738f * 1.4426950408889634f;  // 1/sqrt(8)*log2(e)

    if (bid < 192) {
        int n0 = (bid % 12) * 128, m0 = (bid / 12) * 128;
        gemm_core(hs_bf, 2048, Wqkv_t, 512, m0, n0, AsS, BsS, acc);
        #pragma unroll
        for (int i = 0; i < 4; ++i) {
            int t0 = m0 + wr * 64 + i * 16 + quad * 4;   // 4 consecutive tokens
            int b_ = t0 >> 10, nn = t0 & 1023;
            #pragma unroll
            for (int j = 0; j < 4; ++j) {
                int col = n0 + wc * 64 + j * 16 + l16;
                float v0 = acc[i][j][0] + bqkv[col];
                float v1 = acc[i][j][1] + bqkv[col];
                float v2 = acc[i][j][2] + bqkv[col];
                float v3 = acc[i][j][3] + bqkv[col];
                if (col < 512) {
                    int h = col >> 3, c = col & 7;
                    unsigned short* qp = Qh + (((size_t)b_ * 64 + h) * 1024 + nn) * 8 + c;
                    qp[0]  = f2bf(v0 * ASCALE);
                    qp[8]  = f2bf(v1 * ASCALE);
                    qp[16] = f2bf(v2 * ASCALE);
                    qp[24] = f2bf(v3 * ASCALE);
                } else if (col < 1024) {
                    int cc = col - 512, h = cc >> 3, c = cc & 7;
                    unsigned short* kp = Kh + (((size_t)b_ * 64 + h) * KROWS + nn) * 8 + c;
                    kp[0]  = f2bf(v0);
                    kp[8]  = f2bf(v1);
                    kp[16] = f2bf(v2);
                    kp[24] = f2bf(v3);
                } else {
                    int cc = col - 1024, h = cc >> 3, c = cc & 7;
                    ushortx4 pk = { f2bf(v0), f2bf(v1), f2bf(v2), f2bf(v3) };
                    *(ushortx4*)(Vh + (((size_t)b_ * 64 + h) * 16 + c) * KROWS + nn) = pk;
                }
            }
        }
    } else {
        int idx = bid - 192;
        int n0 = (idx % 8) * 128, m0 = (idx / 8) * 128;
        gemm_core(enc_bf, 154, Wakv_t, 768, m0, n0, AsS, BsS, acc);
        #pragma unroll
        for (int i = 0; i < 4; ++i) {
            int rg0 = m0 + wr * 64 + i * 16 + quad * 4;
            #pragma unroll
            for (int j = 0; j < 4; ++j) {
                int col = n0 + wc * 64 + j * 16 + l16;
                #pragma unroll
                for (int r = 0; r < 4; ++r) {
                    int rg = rg0 + r;
                    if (rg < 154) {
                        int b_ = rg >= 77;
                        int jj = rg - 77 * b_;
                        float v = acc[i][j][r] + bakv[col];
                        if (col < 512) {
                            int h = col >> 3, c = col & 7;
                            Kh[(((size_t)b_ * 64 + h) * KROWS + 1024 + jj) * 8 + c] = f2bf(v);
                        } else {
                            int cc = col - 512, h = cc >> 3, c = cc & 7;
                            Vh[(((size_t)b_ * 64 + h) * 16 + c) * KROWS + 1024 + jj] = f2bf(v);
                        }
                    }
                }
            }
        }
    }
}

// ---------------------------------------------------------------- out-projection
// C^T: A=Wo_t [512,512], Bt=AO [2048,512] -> out[(b*512+c)*1024+n] + bias + residual
__global__ __launch_bounds__(256) void gemm_out(
        const unsigned short* __restrict__ Wo_t, const unsigned short* __restrict__ AO,
        const float* __restrict__ bias, const float* __restrict__ resid,
        float* __restrict__ out) {
    __shared__ alignas(16) unsigned short AsS[128 * 32];
    __shared__ alignas(16) unsigned short BsS[128 * 32];
    floatx4 acc[4][4] = {};
    int tid = threadIdx.x;
    int wv = tid >> 6, ln = tid & 63;
    int quad = ln >> 4, l16 = ln & 15;
    int wr = wv >> 1, wc = wv & 1;
    int n0 = blockIdx.x * 128, m0 = blockIdx.y * 128;
    gemm_core(Wo_t, 512, AO, 512, m0, n0, AsS, BsS, acc);
    #pragma unroll
    for (int i = 0; i < 4; ++i) {
        int cbase = m0 + wr * 64 + i * 16 + quad * 4;
        #pragma unroll
        for (int j = 0; j < 4; ++j) {
            int ng = n0 + wc * 64 + j * 16 + l16;
            int b = ng >> 10, n = ng & 1023;
            float4 res = *(const float4*)(resid + ((size_t)(b * 1024 + n)) * 512 + cbase);
            float rr[4] = {res.x, res.y, res.z, res.w};
            #pragma unroll
            for (int r = 0; r < 4; ++r) {
                int c = cbase + r;
                out[((size_t)(b * 512 + c)) * 1024 + n] = acc[i][j][r] + bias[c] + rr[r];
            }
        }
    }
}

// ---------------------------------------------------------------- MFMA flash attention
// Block = (b, h, qtile of 128); 4 waves x 32 queries (2 16q-subtiles sharing K/V).
// S = mfma(K_frag, Q_frag) -> C[kv][q]: lane holds q=l16 fixed, kv=quad*4+r runs
// -> P stored row-major P[q][kv] with ONE ds_write_b64 per 16kv, read back as
// the PV A-frag with ONE ds_read_b128. Fixed-max softmax (m=0, exact here);
// l = sum(p) via ones-row at V ch=8. No barriers.
__global__ __launch_bounds__(256) void attn_mfma(
        const unsigned short* __restrict__ Qh,   // [2][64][1024][8]
        const unsigned short* __restrict__ Kh,   // [2][64][KROWS][8]
        const unsigned short* __restrict__ Vh,   // [2][64][16][KROWS]
        unsigned short* __restrict__ AO) {       // [2048][512]
    __shared__ alignas(16) unsigned short P_lds[4][2][16][40];
    int x = blockIdx.x;
    int h = x & 63, qt = (x >> 6) & 7, b = x >> 9;
    int tid = threadIdx.x, wv = tid >> 6, ln = tid & 63;
    int quad = ln >> 4, l16 = ln & 15;
    int q0r = qt * 128 + wv * 32;
    int bh = b * 64 + h;

    short8 qa = {}, qb = {};
    if (quad == 0) {
        qa = *(const short8*)(Qh + ((size_t)bh * 1024 + q0r + l16) * 8);
        qb = *(const short8*)(Qh + ((size_t)bh * 1024 + q0r + 16 + l16) * 8);
    }
    const unsigned short* Kb = Kh + (size_t)bh * KROWS * 8;
    const unsigned short* Vb = Vh + ((size_t)bh * 16 + l16) * KROWS;

    floatx4 acca = {}, accb = {};
    unsigned short* Pa = &P_lds[wv][0][0][0];
    unsigned short* Pb = &P_lds[wv][1][0][0];

    for (int base = 0; base < 1088; base += 32) {
        short8 k0 = *(const short8*)(Kb + (size_t)(base + l16) * 8);
        short8 k1 = *(const short8*)(Kb + (size_t)(base + 16 + l16) * 8);
        short8 vf = *(const short8*)(Vb + base + quad * 8);
        floatx4 z = {};
        floatx4 s0a = __builtin_amdgcn_mfma_f32_16x16x32_bf16(k0, qa, z, 0, 0, 0);
        floatx4 s1a = __builtin_amdgcn_mfma_f32_16x16x32_bf16(k1, qa, z, 0, 0, 0);
        floatx4 s0b = __builtin_amdgcn_mfma_f32_16x16x32_bf16(k0, qb, z, 0, 0, 0);
        floatx4 s1b = __builtin_amdgcn_mfma_f32_16x16x32_bf16(k1, qb, z, 0, 0, 0);
        ushortx4 w0a, w1a, w0b, w1b;
        #pragma unroll
        for (int r = 0; r < 4; ++r) {
            w0a[r] = rtzbf(__builtin_amdgcn_exp2f(s0a[r]));
            w1a[r] = rtzbf(__builtin_amdgcn_exp2f(s1a[r]));
            w0b[r] = rtzbf(__builtin_amdgcn_exp2f(s0b[r]));
            w1b[r] = rtzbf(__builtin_amdgcn_exp2f(s1b[r]));
        }
        *(ushortx4*)(Pa + l16 * 40 + quad * 4)      = w0a;
        *(ushortx4*)(Pa + l16 * 40 + 16 + quad * 4) = w1a;
        *(ushortx4*)(Pb + l16 * 40 + quad * 4)      = w0b;
        *(ushortx4*)(Pb + l16 * 40 + 16 + quad * 4) = w1b;
        short8 pfa = *(const short8*)(Pa + l16 * 40 + quad * 8);
        short8 pfb = *(const short8*)(Pb + l16 * 40 + quad * 8);
        acca = __builtin_amdgcn_mfma_f32_16x16x32_bf16(pfa, vf, acca, 0, 0, 0);
        accb = __builtin_amdgcn_mfma_f32_16x16x32_bf16(pfb, vf, accb, 0, 0, 0);
    }
    {   // tail chunk base=1088: valid kv 1088..1100 (13 of 32)
        short8 k0 = *(const short8*)(Kb + (size_t)(1088 + l16) * 8);
        short8 vf = *(const short8*)(Vb + 1088 + quad * 8);
        floatx4 z = {};
        floatx4 s0a = __builtin_amdgcn_mfma_f32_16x16x32_bf16(k0, qa, z, 0, 0, 0);
        floatx4 s0b = __builtin_amdgcn_mfma_f32_16x16x32_bf16(k0, qb, z, 0, 0, 0);
        ushortx4 w0a, w0b, wz;
        #pragma unroll
        for (int r = 0; r < 4; ++r) {
            bool valid = (quad * 4 + r) < 13;
            w0a[r] = valid ? rtzbf(__builtin_amdgcn_exp2f(s0a[r])) : (unsigned short)0;
            w0b[r] = valid ? rtzbf(__builtin_amdgcn_exp2f(s0b[r])) : (unsigned short)0;
            wz[r] = 0;
        }
        *(ushortx4*)(Pa + l16 * 40 + quad * 4)      = w0a;
        *(ushortx4*)(Pa + l16 * 40 + 16 + quad * 4) = wz;
        *(ushortx4*)(Pb + l16 * 40 + quad * 4)      = w0b;
        *(ushortx4*)(Pb + l16 * 40 + 16 + quad * 4) = wz;
        short8 pfa = *(const short8*)(Pa + l16 * 40 + quad * 8);
        short8 pfb = *(const short8*)(Pb + l16 * 40 + quad * 8);
        acca = __builtin_amdgcn_mfma_f32_16x16x32_bf16(pfa, vf, acca, 0, 0, 0);
        accb = __builtin_amdgcn_mfma_f32_16x16x32_bf16(pfb, vf, accb, 0, 0, 0);
    }

    #pragma unroll
    for (int r = 0; r < 4; ++r) {
        float la = __shfl(acca[r], (ln & 48) + 8, 64);    // l from ones-column (ch=8)
        float lb = __shfl(accb[r], (ln & 48) + 8, 64);
        if (l16 < 8) {
            AO[((size_t)(b * 1024 + q0r + quad * 4 + r)) * 512 + h * 8 + l16] =
                f2bf(acca[r] / la);
            AO[((size_t)(b * 1024 + q0r + 16 + quad * 4 + r)) * 512 + h * 8 + l16] =
                f2bf(accb[r] / lb);
        }
    }
}

// ---------------------------------------------------------------- launcher
extern "C" void kernel_launch(void* const* d_in, const int* in_sizes, int n_in,
                              void* d_out, int out_size, void* d_ws, size_t ws_size,
                              hipStream_t stream) {
    const float* x    = (const float*)d_in[0];
    const float* enc  = (const float*)d_in[1];
    const float* gn_s = (const float*)d_in[2];
    const float* gn_b = (const float*)d_in[3];
    const float* ln_s = (const float*)d_in[4];
    const float* ln_b = (const float*)d_in[5];
    const float* Wq  = (const float*)d_in[6];   const float* bq  = (const float*)d_in[7];
    const float* Wk  = (const float*)d_in[8];   const float* bk  = (const float*)d_in[9];
    const float* Wv  = (const float*)d_in[10];  const float* bv  = (const float*)d_in[11];
    const float* Wak = (const float*)d_in[12];  const float* bak = (const float*)d_in[13];
    const float* Wav = (const float*)d_in[14];  const float* bav = (const float*)d_in[15];
    const float* Wo  = (const float*)d_in[16];  const float* bo  = (const float*)d_in[17];
    float* out = (float*)d_out;

    char* p = (char*)d_ws;
    auto alloc = [&](size_t bytes) { char* r = p; p += (bytes + 255) & ~255ULL; return r; };
    unsigned short* hs_bf  = (unsigned short*)alloc((size_t)2048 * 512 * 2);
    unsigned short* enc_bf = (unsigned short*)alloc((size_t)154 * 768 * 2);
    unsigned short* Wqkv_t = (unsigned short*)alloc((size_t)1536 * 512 * 2);
    unsigned short* Wakv_t = (unsigned short*)alloc((size_t)1024 * 768 * 2);
    unsigned short* Wo_t   = (unsigned short*)alloc((size_t)512 * 512 * 2);
    float* bqkv = (float*)alloc(1536 * 4);
    float* bakv = (float*)alloc(1024 * 4);
    unsigned short* Qh = (unsigned short*)alloc((size_t)2 * 64 * 1024 * 8 * 2);
    unsigned short* Kh = (unsigned short*)alloc((size_t)2 * 64 * KROWS * 8 * 2);
    unsigned short* Vh = (unsigned short*)alloc((size_t)2 * 64 * 16 * KROWS * 2);
    unsigned short* AO = (unsigned short*)alloc((size_t)2048 * 512 * 2);

    prep_all<<<2580, 256, 0, stream>>>(
        Wq, Wk, Wv, Wak, Wav, Wo, bq, bk, bv, bak, bav,
        enc, ln_s, ln_b, x, gn_s, gn_b,
        Wqkv_t, Wakv_t, Wo_t, bqkv, bakv, enc_bf, hs_bf, Vh);

    proj_gemm<<<208, 256, 0, stream>>>(
        hs_bf, enc_bf, Wqkv_t, Wakv_t, bqkv, bakv, Qh, Kh, Vh);

    attn_mfma<<<BSZ * NHEAD * 8, 256, 0, stream>>>(Qh, Kh, Vh, AO);

    gemm_out<<<dim3(16, 4), 256, 0, stream>>>(Wo_t, AO, bo, x, out);

    (void)in_sizes; (void)n_in; (void)out_size; (void)ws_size;
}

// Round 8
// 156.183 us; speedup vs baseline: 2.3765x; 1.1647x over previous
//
#include <hip/hip_runtime.h>
#include <math.h>

// Problem constants
#define BSZ   2
#define NTOK  1024          // 32*32
#define CDIM  512
#define SENC  77
#define SKV   1101          // 77 + 1024 (order: self rows 0..1023, enc rows 1024..1100)
#define KROWS 1120          // padded KV rows (35 chunks of 32)
#define ENCD  768
#define NHEAD 64
#define DHEAD 8

typedef short short8 __attribute__((ext_vector_type(8)));
typedef float floatx4 __attribute__((ext_vector_type(4)));
typedef unsigned short ushortx4 __attribute__((ext_vector_type(4)));

__device__ __forceinline__ unsigned short f2bf(float f) {
    union { float f; unsigned int u; } v; v.f = f;
    unsigned int r = v.u + 0x7FFF + ((v.u >> 16) & 1);   // RNE
    return (unsigned short)(r >> 16);
}
__device__ __forceinline__ unsigned short rtzbf(float f) {
    return (unsigned short)(__float_as_uint(f) >> 16);   // RTZ (cancels in softmax norm)
}

// C-style casts: clang only allows addrspacecast via C-style
__device__ __forceinline__ void gld16(const void* g, void* l) {
    __builtin_amdgcn_global_load_lds(
        (const __attribute__((address_space(1))) unsigned int*)g,
        (__attribute__((address_space(3))) unsigned int*)l,
        16, 0, 0);
}

// ---------------------------------------------------------------- reductions
__device__ __forceinline__ float block_reduce_sum(float v) {
    #pragma unroll
    for (int off = 32; off > 0; off >>= 1) v += __shfl_down(v, off, 64);
    __shared__ float tmp[4];
    int lane = threadIdx.x & 63, wid = threadIdx.x >> 6;
    if (lane == 0) tmp[wid] = v;
    __syncthreads();
    if (wid == 0) {
        float r = (lane < 4) ? tmp[lane] : 0.f;
        r += __shfl_down(r, 2, 64);
        r += __shfl_down(r, 1, 64);
        if (lane == 0) tmp[0] = r;
    }
    __syncthreads();
    float out = tmp[0];
    __syncthreads();
    return out;
}

// ---------------------------------------------------------------- prep device parts
__device__ void layernorm_dev(int row, const float* __restrict__ x,
                              const float* __restrict__ sc, const float* __restrict__ bi,
                              unsigned short* __restrict__ out) {
    const float* xp = x + (size_t)row * ENCD;
    unsigned short* op = out + (size_t)row * ENCD;
    int t = threadIdx.x;
    float v0 = xp[t], v1 = xp[t + 256], v2 = xp[t + 512];
    float mu = block_reduce_sum(v0 + v1 + v2) * (1.f / ENCD);
    float d0 = v0 - mu, d1 = v1 - mu, d2 = v2 - mu;
    float var = block_reduce_sum(d0 * d0 + d1 * d1 + d2 * d2) * (1.f / ENCD);
    float rstd = rsqrtf(var + 1e-5f);
    op[t]       = f2bf(d0 * rstd * sc[t]       + bi[t]);
    op[t + 256] = f2bf(d1 * rstd * sc[t + 256] + bi[t + 256]);
    op[t + 512] = f2bf(d2 * rstd * sc[t + 512] + bi[t + 512]);
}

// single-pass register-resident GroupNorm: 16 independent float4 loads/thread,
// sum+sumsq in one pass (var = E[x^2]-mu^2), normalize from registers.
__device__ void groupnorm_dev(int bg, const float* __restrict__ x,
                              const float* __restrict__ sc, const float* __restrict__ bi,
                              unsigned short* __restrict__ out) {
    int b = bg >> 5, g = bg & 31;
    const float* xp = x + (size_t)b * NTOK * CDIM + g * 16;
    unsigned short* op = out + (size_t)b * NTOK * CDIM + g * 16;
    int t = threadIdx.x;
    int q = t & 3;                        // (t + it*256) & 3 == t & 3

    float4 v[16];
    #pragma unroll
    for (int it = 0; it < 16; ++it) {
        int idx = t + it * 256;
        int n = idx >> 2;
        v[it] = *(const float4*)(xp + n * CDIM + q * 4);
    }
    float s = 0.f, ss = 0.f;
    #pragma unroll
    for (int it = 0; it < 16; ++it) {
        s  += (v[it].x + v[it].y) + (v[it].z + v[it].w);
        ss += (v[it].x * v[it].x + v[it].y * v[it].y)
            + (v[it].z * v[it].z + v[it].w * v[it].w);
    }
    float mu  = block_reduce_sum(s)  * (1.f / 16384.f);
    float msq = block_reduce_sum(ss) * (1.f / 16384.f);
    float rstd = rsqrtf(msq - mu * mu + 1e-5f);

    float4 s4 = *(const float4*)(sc + g * 16 + q * 4);
    float4 b4 = *(const float4*)(bi + g * 16 + q * 4);
    #pragma unroll
    for (int it = 0; it < 16; ++it) {
        int idx = t + it * 256;
        int n = idx >> 2;
        ushortx4 o;
        o[0] = f2bf((v[it].x - mu) * rstd * s4.x + b4.x);
        o[1] = f2bf((v[it].y - mu) * rstd * s4.y + b4.y);
        o[2] = f2bf((v[it].z - mu) * rstd * s4.z + b4.z);
        o[3] = f2bf((v[it].w - mu) * rstd * s4.w + b4.w);
        *(ushortx4*)(op + n * CDIM + q * 4) = o;
    }
}

// transpose+cast one 32x32 tile: W[K][N] fp32 -> Wt[N+roff][K] bf16
__device__ void tcast_dev(const float* __restrict__ W, unsigned short* __restrict__ Wt,
                          int K, int N, int roff, int local) {
    __shared__ float t[32][33];
    int bn = (local & 15) * 32, bk = (local >> 4) * 32;
    int lx = threadIdx.x & 31, ly = threadIdx.x >> 5;
    #pragma unroll
    for (int r = 0; r < 4; ++r)
        t[ly + 8 * r][lx] = W[(size_t)(bk + ly + 8 * r) * N + bn + lx];
    __syncthreads();
    #pragma unroll
    for (int r = 0; r < 4; ++r)
        Wt[(size_t)(roff + bn + ly + 8 * r) * K + bk + lx] = f2bf(t[lx][ly + 8 * r]);
}

// ---------------------------------------------------------------- fused preprocessing
__global__ __launch_bounds__(256) void prep_all(
        const float* __restrict__ Wq, const float* __restrict__ Wk, const float* __restrict__ Wv,
        const float* __restrict__ Wak, const float* __restrict__ Wav, const float* __restrict__ Wo,
        const float* __restrict__ bq, const float* __restrict__ bk, const float* __restrict__ bv,
        const float* __restrict__ bak, const float* __restrict__ bav,
        const float* __restrict__ enc, const float* __restrict__ ln_s, const float* __restrict__ ln_b,
        const float* __restrict__ x, const float* __restrict__ gn_s, const float* __restrict__ gn_b,
        unsigned short* __restrict__ Wqkv_t, unsigned short* __restrict__ Wakv_t,
        unsigned short* __restrict__ Wo_t,
        float* __restrict__ bqkv, float* __restrict__ bakv,
        unsigned short* __restrict__ enc_bf, unsigned short* __restrict__ hs_bf,
        unsigned short* __restrict__ Vh) {
    int bid = blockIdx.x;
    if (bid < 256)        tcast_dev(Wq,  Wqkv_t, 512, 512, 0,    bid);
    else if (bid < 512)   tcast_dev(Wk,  Wqkv_t, 512, 512, 512,  bid - 256);
    else if (bid < 768)   tcast_dev(Wv,  Wqkv_t, 512, 512, 1024, bid - 512);
    else if (bid < 1152)  tcast_dev(Wak, Wakv_t, 768, 512, 0,    bid - 768);
    else if (bid < 1536)  tcast_dev(Wav, Wakv_t, 768, 512, 512,  bid - 1152);
    else if (bid < 1792)  tcast_dev(Wo,  Wo_t,   512, 512, 0,    bid - 1536);
    else if (bid < 1802) {
        int i = (bid - 1792) * 256 + threadIdx.x;
        if (i < 512)        bqkv[i] = bq[i];
        else if (i < 1024)  bqkv[i] = bk[i - 512];
        else if (i < 1536)  bqkv[i] = bv[i - 1024];
        else if (i < 2048)  bakv[i - 1536] = bak[i - 1536];
        else if (i < 2560)  bakv[i - 1536] = bav[i - 2048];
    }
    else if (bid < 1956)  layernorm_dev(bid - 1802, enc, ln_s, ln_b, enc_bf);
    else if (bid < 2020)  groupnorm_dev(bid - 1956, x, gn_s, gn_b, hs_bf);
    else {
        // ones-row (ch=8) of Vh for the l=sum(p) trick: 2*64*1120 = 143360 elems
        int i = (bid - 2020) * 256 + threadIdx.x;   // [0, 143360)
        int g = i / KROWS, kv = i - g * KROWS;      // g = b*64+h
        Vh[((size_t)g * 16 + 8) * KROWS + kv] = 0x3F80;  // bf16 1.0
    }
}

// ---------------------------------------------------------------- shared GEMM core
// 128x128 tile, 4 waves 2x2, 16x16x32 bf16 MFMA, global_load_lds staging.
// SWAP=false: acc[i][j] = C[token-in-regs][col-in-lanes]
// SWAP=true : acc[i][j] = C[col-in-regs][token-in-lanes]  (operands swapped)
template <bool SWAP>
__device__ __forceinline__ void gemm_core(
        const unsigned short* __restrict__ A, int Mv,
        const unsigned short* __restrict__ Bt, int K,
        int m0, int n0, unsigned short* AsS, unsigned short* BsS,
        floatx4 (&acc)[4][4]) {
    int tid = threadIdx.x;
    int wv = tid >> 6, ln = tid & 63;
    int quad = ln >> 4, l16 = ln & 15;
    int wr = wv >> 1, wc = wv & 1;

    for (int k0 = 0; k0 < K; k0 += 32) {
        #pragma unroll
        for (int it = 0; it < 2; ++it) {
            int cb = it * 256 + wv * 64;
            int c = cb + ln;
            int r = c >> 2, sg = c & 3;
            int row = m0 + r; if (row > Mv - 1) row = Mv - 1;
            gld16((const void*)(A + (size_t)row * K + k0 + sg * 8),
                  (void*)((char*)AsS + cb * 16));
            gld16((const void*)(Bt + (size_t)(n0 + r) * K + k0 + sg * 8),
                  (void*)((char*)BsS + cb * 16));
        }
        __syncthreads();
        short8 af[4], bf[4];
        #pragma unroll
        for (int i = 0; i < 4; ++i)
            af[i] = *(const short8*)(AsS + (wr * 64 + i * 16 + l16) * 32 + quad * 8);
        #pragma unroll
        for (int j = 0; j < 4; ++j)
            bf[j] = *(const short8*)(BsS + (wc * 64 + j * 16 + l16) * 32 + quad * 8);
        #pragma unroll
        for (int i = 0; i < 4; ++i)
            #pragma unroll
            for (int j = 0; j < 4; ++j)
                acc[i][j] = SWAP
                    ? __builtin_amdgcn_mfma_f32_16x16x32_bf16(bf[j], af[i], acc[i][j], 0, 0, 0)
                    : __builtin_amdgcn_mfma_f32_16x16x32_bf16(af[i], bf[j], acc[i][j], 0, 0, 0);
        __syncthreads();
    }
}

// ---------------------------------------------------------------- merged projections
// blocks [0,192): QKV [2048,512]x[512,1536] -> head-major Qh/Kh/Vh
// blocks [192,208): enc KV [154,768]x[768,1024] -> Kh/Vh rows 1024+
// SWAPped core: regs hold 4 consecutive output cols of ONE token (lane) ->
// Q/K stores are single 8B ushortx4; V stores lane-coalesced 2B runs.
__global__ __launch_bounds__(256) void proj_gemm(
        const unsigned short* __restrict__ hs_bf, const unsigned short* __restrict__ enc_bf,
        const unsigned short* __restrict__ Wqkv_t, const unsigned short* __restrict__ Wakv_t,
        const float* __restrict__ bqkv, const float* __restrict__ bakv,
        unsigned short* __restrict__ Qh, unsigned short* __restrict__ Kh,
        unsigned short* __restrict__ Vh) {
    __shared__ alignas(16) unsigned short AsS[128 * 32];
    __shared__ alignas(16) unsigned short BsS[128 * 32];
    floatx4 acc[4][4] = {};
    int bid = blockIdx.x;
    int tid = threadIdx.x;
    int wv = tid >> 6, ln = tid & 63;
    int quad = ln >> 4, l16 = ln & 15;
    int wr = wv >> 1, wc = wv & 1;
    const float ASCALE = 0.3535533905932738f * 1.4426950408889634f;  // 1/sqrt(8)*log2(e)

    if (bid < 192) {
        int n0 = (bid % 12) * 128, m0 = (bid / 12) * 128;
        gemm_core<true>(hs_bf, 2048, Wqkv_t, 512, m0, n0, AsS, BsS, acc);
        #pragma unroll
        for (int i = 0; i < 4; ++i) {
            int tok = m0 + wr * 64 + i * 16 + l16;      // lane-varying token
            int b_ = tok >> 10, nn = tok & 1023;
            #pragma unroll
            for (int j = 0; j < 4; ++j) {
                int colb = n0 + wc * 64 + j * 16 + quad * 4;   // wave-uniform
                float vv[4];
                #pragma unroll
                for (int r = 0; r < 4; ++r) vv[r] = acc[i][j][r] + bqkv[colb + r];
                if (colb < 512) {
                    int h = colb >> 3, c = colb & 7;
                    ushortx4 w = { f2bf(vv[0] * ASCALE), f2bf(vv[1] * ASCALE),
                                   f2bf(vv[2] * ASCALE), f2bf(vv[3] * ASCALE) };
                    *(ushortx4*)(Qh + ((size_t)(b_ * 64 + h) * 1024 + nn) * 8 + c) = w;
                } else if (colb < 1024) {
                    int cc = colb - 512, h = cc >> 3, c = cc & 7;
                    ushortx4 w = { f2bf(vv[0]), f2bf(vv[1]), f2bf(vv[2]), f2bf(vv[3]) };
                    *(ushortx4*)(Kh + ((size_t)(b_ * 64 + h) * KROWS + nn) * 8 + c) = w;
                } else {
                    int cc = colb - 1024, h = cc >> 3, c = cc & 7;
                    #pragma unroll
                    for (int r = 0; r < 4; ++r)
                        Vh[((size_t)(b_ * 64 + h) * 16 + c + r) * KROWS + nn] = f2bf(vv[r]);
                }
            }
        }
    } else {
        int idx = bid - 192;
        int n0 = (idx % 8) * 128, m0 = (idx / 8) * 128;
        gemm_core<true>(enc_bf, 154, Wakv_t, 768, m0, n0, AsS, BsS, acc);
        #pragma unroll
        for (int i = 0; i < 4; ++i) {
            int rg = m0 + wr * 64 + i * 16 + l16;       // lane-varying enc token
            bool ok = rg < 154;
            int b_ = rg >= 77;
            int jj = rg - 77 * b_;
            #pragma unroll
            for (int j = 0; j < 4; ++j) {
                int colb = n0 + wc * 64 + j * 16 + quad * 4;
                float vv[4];
                #pragma unroll
                for (int r = 0; r < 4; ++r) vv[r] = acc[i][j][r] + bakv[colb + r];
                if (colb < 512) {
                    int h = colb >> 3, c = colb & 7;
                    if (ok) {
                        ushortx4 w = { f2bf(vv[0]), f2bf(vv[1]), f2bf(vv[2]), f2bf(vv[3]) };
                        *(ushortx4*)(Kh + ((size_t)(b_ * 64 + h) * KROWS + 1024 + jj) * 8 + c) = w;
                    }
                } else {
                    int cc = colb - 512, h = cc >> 3, c = cc & 7;
                    if (ok) {
                        #pragma unroll
                        for (int r = 0; r < 4; ++r)
                            Vh[((size_t)(b_ * 64 + h) * 16 + c + r) * KROWS + 1024 + jj] = f2bf(vv[r]);
                    }
                }
            }
        }
    }
}

// ---------------------------------------------------------------- out-projection
// C^T: A=Wo_t [512,512], Bt=AO [2048,512] -> out[(b*512+c)*1024+n] + bias + residual
__global__ __launch_bounds__(256) void gemm_out(
        const unsigned short* __restrict__ Wo_t, const unsigned short* __restrict__ AO,
        const float* __restrict__ bias, const float* __restrict__ resid,
        float* __restrict__ out) {
    __shared__ alignas(16) unsigned short AsS[128 * 32];
    __shared__ alignas(16) unsigned short BsS[128 * 32];
    floatx4 acc[4][4] = {};
    int tid = threadIdx.x;
    int wv = tid >> 6, ln = tid & 63;
    int quad = ln >> 4, l16 = ln & 15;
    int wr = wv >> 1, wc = wv & 1;
    int n0 = blockIdx.x * 128, m0 = blockIdx.y * 128;
    gemm_core<false>(Wo_t, 512, AO, 512, m0, n0, AsS, BsS, acc);
    #pragma unroll
    for (int i = 0; i < 4; ++i) {
        int cbase = m0 + wr * 64 + i * 16 + quad * 4;
        #pragma unroll
        for (int j = 0; j < 4; ++j) {
            int ng = n0 + wc * 64 + j * 16 + l16;
            int b = ng >> 10, n = ng & 1023;
            float4 res = *(const float4*)(resid + ((size_t)(b * 1024 + n)) * 512 + cbase);
            float rr[4] = {res.x, res.y, res.z, res.w};
            #pragma unroll
            for (int r = 0; r < 4; ++r) {
                int c = cbase + r;
                out[((size_t)(b * 512 + c)) * 1024 + n] = acc[i][j][r] + bias[c] + rr[r];
            }
        }
    }
}

// ---------------------------------------------------------------- MFMA flash attention
// Block = (b, h, qtile of 128); 4 waves x 32 queries (2 16q-subtiles sharing K/V).
// S = mfma(K_frag, Q_frag) -> C[kv][q]; P row-major via one ds_write_b64 per 16kv,
// read back as PV A-frag with one ds_read_b128. Fixed-max softmax (m=0, exact);
// l = sum(p) via ones-row at V ch=8. No barriers.
__global__ __launch_bounds__(256) void attn_mfma(
        const unsigned short* __restrict__ Qh,   // [2][64][1024][8]
        const unsigned short* __restrict__ Kh,   // [2][64][KROWS][8]
        const unsigned short* __restrict__ Vh,   // [2][64][16][KROWS]
        unsigned short* __restrict__ AO) {       // [2048][512]
    __shared__ alignas(16) unsigned short P_lds[4][2][16][40];
    int x = blockIdx.x;
    int h = x & 63, qt = (x >> 6) & 7, b = x >> 9;
    int tid = threadIdx.x, wv = tid >> 6, ln = tid & 63;
    int quad = ln >> 4, l16 = ln & 15;
    int q0r = qt * 128 + wv * 32;
    int bh = b * 64 + h;

    short8 qa = {}, qb = {};
    if (quad == 0) {
        qa = *(const short8*)(Qh + ((size_t)bh * 1024 + q0r + l16) * 8);
        qb = *(const short8*)(Qh + ((size_t)bh * 1024 + q0r + 16 + l16) * 8);
    }
    const unsigned short* Kb = Kh + (size_t)bh * KROWS * 8;
    const unsigned short* Vb = Vh + ((size_t)bh * 16 + l16) * KROWS;

    floatx4 acca = {}, accb = {};
    unsigned short* Pa = &P_lds[wv][0][0][0];
    unsigned short* Pb = &P_lds[wv][1][0][0];

    for (int base = 0; base < 1088; base += 32) {
        short8 k0 = *(const short8*)(Kb + (size_t)(base + l16) * 8);
        short8 k1 = *(const short8*)(Kb + (size_t)(base + 16 + l16) * 8);
        short8 vf = *(const short8*)(Vb + base + quad * 8);
        floatx4 z = {};
        floatx4 s0a = __builtin_amdgcn_mfma_f32_16x16x32_bf16(k0, qa, z, 0, 0, 0);
        floatx4 s1a = __builtin_amdgcn_mfma_f32_16x16x32_bf16(k1, qa, z, 0, 0, 0);
        floatx4 s0b = __builtin_amdgcn_mfma_f32_16x16x32_bf16(k0, qb, z, 0, 0, 0);
        floatx4 s1b = __builtin_amdgcn_mfma_f32_16x16x32_bf16(k1, qb, z, 0, 0, 0);
        ushortx4 w0a, w1a, w0b, w1b;
        #pragma unroll
        for (int r = 0; r < 4; ++r) {
            w0a[r] = rtzbf(__builtin_amdgcn_exp2f(s0a[r]));
            w1a[r] = rtzbf(__builtin_amdgcn_exp2f(s1a[r]));
            w0b[r] = rtzbf(__builtin_amdgcn_exp2f(s0b[r]));
            w1b[r] = rtzbf(__builtin_amdgcn_exp2f(s1b[r]));
        }
        *(ushortx4*)(Pa + l16 * 40 + quad * 4)      = w0a;
        *(ushortx4*)(Pa + l16 * 40 + 16 + quad * 4) = w1a;
        *(ushortx4*)(Pb + l16 * 40 + quad * 4)      = w0b;
        *(ushortx4*)(Pb + l16 * 40 + 16 + quad * 4) = w1b;
        short8 pfa = *(const short8*)(Pa + l16 * 40 + quad * 8);
        short8 pfb = *(const short8*)(Pb + l16 * 40 + quad * 8);
        acca = __builtin_amdgcn_mfma_f32_16x16x32_bf16(pfa, vf, acca, 0, 0, 0);
        accb = __builtin_amdgcn_mfma_f32_16x16x32_bf16(pfb, vf, accb, 0, 0, 0);
    }
    {   // tail chunk base=1088: valid kv 1088..1100 (13 of 32)
        short8 k0 = *(const short8*)(Kb + (size_t)(1088 + l16) * 8);
        short8 vf = *(const short8*)(Vb + 1088 + quad * 8);
        floatx4 z = {};
        floatx4 s0a = __builtin_amdgcn_mfma_f32_16x16x32_bf16(k0, qa, z, 0, 0, 0);
        floatx4 s0b = __builtin_amdgcn_mfma_f32_16x16x32_bf16(k0, qb, z, 0, 0, 0);
        ushortx4 w0a, w0b, wz;
        #pragma unroll
        for (int r = 0; r < 4; ++r) {
            bool valid = (quad * 4 + r) < 13;
            w0a[r] = valid ? rtzbf(__builtin_amdgcn_exp2f(s0a[r])) : (unsigned short)0;
            w0b[r] = valid ? rtzbf(__builtin_amdgcn_exp2f(s0b[r])) : (unsigned short)0;
            wz[r] = 0;
        }
        *(ushortx4*)(Pa + l16 * 40 + quad * 4)      = w0a;
        *(ushortx4*)(Pa + l16 * 40 + 16 + quad * 4) = wz;
        *(ushortx4*)(Pb + l16 * 40 + quad * 4)      = w0b;
        *(ushortx4*)(Pb + l16 * 40 + 16 + quad * 4) = wz;
        short8 pfa = *(const short8*)(Pa + l16 * 40 + quad * 8);
        short8 pfb = *(const short8*)(Pb + l16 * 40 + quad * 8);
        acca = __builtin_amdgcn_mfma_f32_16x16x32_bf16(pfa, vf, acca, 0, 0, 0);
        accb = __builtin_amdgcn_mfma_f32_16x16x32_bf16(pfb, vf, accb, 0, 0, 0);
    }

    #pragma unroll
    for (int r = 0; r < 4; ++r) {
        float la = __shfl(acca[r], (ln & 48) + 8, 64);    // l from ones-column (ch=8)
        float lb = __shfl(accb[r], (ln & 48) + 8, 64);
        if (l16 < 8) {
            AO[((size_t)(b * 1024 + q0r + quad * 4 + r)) * 512 + h * 8 + l16] =
                f2bf(acca[r] / la);
            AO[((size_t)(b * 1024 + q0r + 16 + quad * 4 + r)) * 512 + h * 8 + l16] =
                f2bf(accb[r] / lb);
        }
    }
}

// ---------------------------------------------------------------- launcher
extern "C" void kernel_launch(void* const* d_in, const int* in_sizes, int n_in,
                              void* d_out, int out_size, void* d_ws, size_t ws_size,
                              hipStream_t stream) {
    const float* x    = (const float*)d_in[0];
    const float* enc  = (const float*)d_in[1];
    const float* gn_s = (const float*)d_in[2];
    const float* gn_b = (const float*)d_in[3];
    const float* ln_s = (const float*)d_in[4];
    const float* ln_b = (const float*)d_in[5];
    const float* Wq  = (const float*)d_in[6];   const float* bq  = (const float*)d_in[7];
    const float* Wk  = (const float*)d_in[8];   const float* bk  = (const float*)d_in[9];
    const float* Wv  = (const float*)d_in[10];  const float* bv  = (const float*)d_in[11];
    const float* Wak = (const float*)d_in[12];  const float* bak = (const float*)d_in[13];
    const float* Wav = (const float*)d_in[14];  const float* bav = (const float*)d_in[15];
    const float* Wo  = (const float*)d_in[16];  const float* bo  = (const float*)d_in[17];
    float* out = (float*)d_out;

    char* p = (char*)d_ws;
    auto alloc = [&](size_t bytes) { char* r = p; p += (bytes + 255) & ~255ULL; return r; };
    unsigned short* hs_bf  = (unsigned short*)alloc((size_t)2048 * 512 * 2);
    unsigned short* enc_bf = (unsigned short*)alloc((size_t)154 * 768 * 2);
    unsigned short* Wqkv_t = (unsigned short*)alloc((size_t)1536 * 512 * 2);
    unsigned short* Wakv_t = (unsigned short*)alloc((size_t)1024 * 768 * 2);
    unsigned short* Wo_t   = (unsigned short*)alloc((size_t)512 * 512 * 2);
    float* bqkv = (float*)alloc(1536 * 4);
    float* bakv = (float*)alloc(1024 * 4);
    unsigned short* Qh = (unsigned short*)alloc((size_t)2 * 64 * 1024 * 8 * 2);
    unsigned short* Kh = (unsigned short*)alloc((size_t)2 * 64 * KROWS * 8 * 2);
    unsigned short* Vh = (unsigned short*)alloc((size_t)2 * 64 * 16 * KROWS * 2);
    unsigned short* AO = (unsigned short*)alloc((size_t)2048 * 512 * 2);

    prep_all<<<2580, 256, 0, stream>>>(
        Wq, Wk, Wv, Wak, Wav, Wo, bq, bk, bv, bak, bav,
        enc, ln_s, ln_b, x, gn_s, gn_b,
        Wqkv_t, Wakv_t, Wo_t, bqkv, bakv, enc_bf, hs_bf, Vh);

    proj_gemm<<<208, 256, 0, stream>>>(
        hs_bf, enc_bf, Wqkv_t, Wakv_t, bqkv, bakv, Qh, Kh, Vh);

    attn_mfma<<<BSZ * NHEAD * 8, 256, 0, stream>>>(Qh, Kh, Vh, AO);

    gemm_out<<<dim3(16, 4), 256, 0, stream>>>(Wo_t, AO, bo, x, out);

    (void)in_sizes; (void)n_in; (void)out_size; (void)ws_size;
}

// Round 9
// 154.242 us; speedup vs baseline: 2.4064x; 1.0126x over previous
//
#include <hip/hip_runtime.h>
#include <math.h>

// Problem constants
#define BSZ   2
#define NTOK  1024          // 32*32
#define CDIM  512
#define SENC  77
#define SKV   1101          // 77 + 1024 (order: self rows 0..1023, enc rows 1024..1100)
#define KROWS 1120          // padded KV rows (35 chunks of 32)
#define ENCD  768
#define NHEAD 64
#define DHEAD 8

typedef short short8 __attribute__((ext_vector_type(8)));
typedef float floatx4 __attribute__((ext_vector_type(4)));
typedef unsigned short ushortx4 __attribute__((ext_vector_type(4)));

__device__ __forceinline__ unsigned short f2bf(float f) {
    union { float f; unsigned int u; } v; v.f = f;
    unsigned int r = v.u + 0x7FFF + ((v.u >> 16) & 1);   // RNE
    return (unsigned short)(r >> 16);
}
__device__ __forceinline__ unsigned short rtzbf(float f) {
    return (unsigned short)(__float_as_uint(f) >> 16);   // RTZ (cancels in softmax norm)
}
// kv-column permutation so S-MFMA output regs ARE the PV A-frag:
// slot(kvrel): kvrel = quad*4+(j&3)+(j>=4)*16  ->  slot = quad*8+j
__device__ __forceinline__ int vslot(int kr) {
    return ((kr & 12) << 1) | ((kr & 16) >> 2) | (kr & 3);
}

// C-style casts: clang only allows addrspacecast via C-style
__device__ __forceinline__ void gld16(const void* g, void* l) {
    __builtin_amdgcn_global_load_lds(
        (const __attribute__((address_space(1))) unsigned int*)g,
        (__attribute__((address_space(3))) unsigned int*)l,
        16, 0, 0);
}

// ---------------------------------------------------------------- reductions
__device__ __forceinline__ float block_reduce_sum(float v) {
    #pragma unroll
    for (int off = 32; off > 0; off >>= 1) v += __shfl_down(v, off, 64);
    __shared__ float tmp[4];
    int lane = threadIdx.x & 63, wid = threadIdx.x >> 6;
    if (lane == 0) tmp[wid] = v;
    __syncthreads();
    if (wid == 0) {
        float r = (lane < 4) ? tmp[lane] : 0.f;
        r += __shfl_down(r, 2, 64);
        r += __shfl_down(r, 1, 64);
        if (lane == 0) tmp[0] = r;
    }
    __syncthreads();
    float out = tmp[0];
    __syncthreads();
    return out;
}

// ---------------------------------------------------------------- prep device parts
__device__ void layernorm_dev(int row, const float* __restrict__ x,
                              const float* __restrict__ sc, const float* __restrict__ bi,
                              unsigned short* __restrict__ out) {
    const float* xp = x + (size_t)row * ENCD;
    unsigned short* op = out + (size_t)row * ENCD;
    int t = threadIdx.x;
    float v0 = xp[t], v1 = xp[t + 256], v2 = xp[t + 512];
    float mu = block_reduce_sum(v0 + v1 + v2) * (1.f / ENCD);
    float d0 = v0 - mu, d1 = v1 - mu, d2 = v2 - mu;
    float var = block_reduce_sum(d0 * d0 + d1 * d1 + d2 * d2) * (1.f / ENCD);
    float rstd = rsqrtf(var + 1e-5f);
    op[t]       = f2bf(d0 * rstd * sc[t]       + bi[t]);
    op[t + 256] = f2bf(d1 * rstd * sc[t + 256] + bi[t + 256]);
    op[t + 512] = f2bf(d2 * rstd * sc[t + 512] + bi[t + 512]);
}

// single-pass register-resident GroupNorm
__device__ void groupnorm_dev(int bg, const float* __restrict__ x,
                              const float* __restrict__ sc, const float* __restrict__ bi,
                              unsigned short* __restrict__ out) {
    int b = bg >> 5, g = bg & 31;
    const float* xp = x + (size_t)b * NTOK * CDIM + g * 16;
    unsigned short* op = out + (size_t)b * NTOK * CDIM + g * 16;
    int t = threadIdx.x;
    int q = t & 3;

    float4 v[16];
    #pragma unroll
    for (int it = 0; it < 16; ++it) {
        int idx = t + it * 256;
        int n = idx >> 2;
        v[it] = *(const float4*)(xp + n * CDIM + q * 4);
    }
    float s = 0.f, ss = 0.f;
    #pragma unroll
    for (int it = 0; it < 16; ++it) {
        s  += (v[it].x + v[it].y) + (v[it].z + v[it].w);
        ss += (v[it].x * v[it].x + v[it].y * v[it].y)
            + (v[it].z * v[it].z + v[it].w * v[it].w);
    }
    float mu  = block_reduce_sum(s)  * (1.f / 16384.f);
    float msq = block_reduce_sum(ss) * (1.f / 16384.f);
    float rstd = rsqrtf(msq - mu * mu + 1e-5f);

    float4 s4 = *(const float4*)(sc + g * 16 + q * 4);
    float4 b4 = *(const float4*)(bi + g * 16 + q * 4);
    #pragma unroll
    for (int it = 0; it < 16; ++it) {
        int idx = t + it * 256;
        int n = idx >> 2;
        ushortx4 o;
        o[0] = f2bf((v[it].x - mu) * rstd * s4.x + b4.x);
        o[1] = f2bf((v[it].y - mu) * rstd * s4.y + b4.y);
        o[2] = f2bf((v[it].z - mu) * rstd * s4.z + b4.z);
        o[3] = f2bf((v[it].w - mu) * rstd * s4.w + b4.w);
        *(ushortx4*)(op + n * CDIM + q * 4) = o;
    }
}

// transpose+cast one 32x32 tile: W[K][N] fp32 -> Wt[N+roff][K] bf16
__device__ void tcast_dev(const float* __restrict__ W, unsigned short* __restrict__ Wt,
                          int K, int N, int roff, int local) {
    __shared__ float t[32][33];
    int bn = (local & 15) * 32, bk = (local >> 4) * 32;
    int lx = threadIdx.x & 31, ly = threadIdx.x >> 5;
    #pragma unroll
    for (int r = 0; r < 4; ++r)
        t[ly + 8 * r][lx] = W[(size_t)(bk + ly + 8 * r) * N + bn + lx];
    __syncthreads();
    #pragma unroll
    for (int r = 0; r < 4; ++r)
        Wt[(size_t)(roff + bn + ly + 8 * r) * K + bk + lx] = f2bf(t[lx][ly + 8 * r]);
}

// ---------------------------------------------------------------- fused preprocessing
__global__ __launch_bounds__(256) void prep_all(
        const float* __restrict__ Wq, const float* __restrict__ Wk, const float* __restrict__ Wv,
        const float* __restrict__ Wak, const float* __restrict__ Wav, const float* __restrict__ Wo,
        const float* __restrict__ bq, const float* __restrict__ bk, const float* __restrict__ bv,
        const float* __restrict__ bak, const float* __restrict__ bav,
        const float* __restrict__ enc, const float* __restrict__ ln_s, const float* __restrict__ ln_b,
        const float* __restrict__ x, const float* __restrict__ gn_s, const float* __restrict__ gn_b,
        unsigned short* __restrict__ Wqkv_t, unsigned short* __restrict__ Wakv_t,
        unsigned short* __restrict__ Wo_t,
        float* __restrict__ bqkv, float* __restrict__ bakv,
        unsigned short* __restrict__ enc_bf, unsigned short* __restrict__ hs_bf,
        unsigned short* __restrict__ Vh) {
    int bid = blockIdx.x;
    if (bid < 256)        tcast_dev(Wq,  Wqkv_t, 512, 512, 0,    bid);
    else if (bid < 512)   tcast_dev(Wk,  Wqkv_t, 512, 512, 512,  bid - 256);
    else if (bid < 768)   tcast_dev(Wv,  Wqkv_t, 512, 512, 1024, bid - 512);
    else if (bid < 1152)  tcast_dev(Wak, Wakv_t, 768, 512, 0,    bid - 768);
    else if (bid < 1536)  tcast_dev(Wav, Wakv_t, 768, 512, 512,  bid - 1152);
    else if (bid < 1792)  tcast_dev(Wo,  Wo_t,   512, 512, 0,    bid - 1536);
    else if (bid < 1802) {
        int i = (bid - 1792) * 256 + threadIdx.x;
        if (i < 512)        bqkv[i] = bq[i];
        else if (i < 1024)  bqkv[i] = bk[i - 512];
        else if (i < 1536)  bqkv[i] = bv[i - 1024];
        else if (i < 2048)  bakv[i - 1536] = bak[i - 1536];
        else if (i < 2560)  bakv[i - 1536] = bav[i - 2048];
    }
    else if (bid < 1956)  layernorm_dev(bid - 1802, enc, ln_s, ln_b, enc_bf);
    else if (bid < 2020)  groupnorm_dev(bid - 1956, x, gn_s, gn_b, hs_bf);
    else {
        // ones-row (ch=8) of Vh for the l=sum(p) trick (permutation-invariant)
        int i = (bid - 2020) * 256 + threadIdx.x;   // [0, 143360)
        int g = i / KROWS, kv = i - g * KROWS;      // g = b*64+h
        Vh[((size_t)g * 16 + 8) * KROWS + kv] = 0x3F80;  // bf16 1.0
    }
}

// ---------------------------------------------------------------- shared GEMM core
template <bool SWAP>
__device__ __forceinline__ void gemm_core(
        const unsigned short* __restrict__ A, int Mv,
        const unsigned short* __restrict__ Bt, int K,
        int m0, int n0, unsigned short* AsS, unsigned short* BsS,
        floatx4 (&acc)[4][4]) {
    int tid = threadIdx.x;
    int wv = tid >> 6, ln = tid & 63;
    int quad = ln >> 4, l16 = ln & 15;
    int wr = wv >> 1, wc = wv & 1;

    for (int k0 = 0; k0 < K; k0 += 32) {
        #pragma unroll
        for (int it = 0; it < 2; ++it) {
            int cb = it * 256 + wv * 64;
            int c = cb + ln;
            int r = c >> 2, sg = c & 3;
            int row = m0 + r; if (row > Mv - 1) row = Mv - 1;
            gld16((const void*)(A + (size_t)row * K + k0 + sg * 8),
                  (void*)((char*)AsS + cb * 16));
            gld16((const void*)(Bt + (size_t)(n0 + r) * K + k0 + sg * 8),
                  (void*)((char*)BsS + cb * 16));
        }
        __syncthreads();
        short8 af[4], bf[4];
        #pragma unroll
        for (int i = 0; i < 4; ++i)
            af[i] = *(const short8*)(AsS + (wr * 64 + i * 16 + l16) * 32 + quad * 8);
        #pragma unroll
        for (int j = 0; j < 4; ++j)
            bf[j] = *(const short8*)(BsS + (wc * 64 + j * 16 + l16) * 32 + quad * 8);
        #pragma unroll
        for (int i = 0; i < 4; ++i)
            #pragma unroll
            for (int j = 0; j < 4; ++j)
                acc[i][j] = SWAP
                    ? __builtin_amdgcn_mfma_f32_16x16x32_bf16(bf[j], af[i], acc[i][j], 0, 0, 0)
                    : __builtin_amdgcn_mfma_f32_16x16x32_bf16(af[i], bf[j], acc[i][j], 0, 0, 0);
        __syncthreads();
    }
}

// ---------------------------------------------------------------- merged projections
__global__ __launch_bounds__(256) void proj_gemm(
        const unsigned short* __restrict__ hs_bf, const unsigned short* __restrict__ enc_bf,
        const unsigned short* __restrict__ Wqkv_t, const unsigned short* __restrict__ Wakv_t,
        const float* __restrict__ bqkv, const float* __restrict__ bakv,
        unsigned short* __restrict__ Qh, unsigned short* __restrict__ Kh,
        unsigned short* __restrict__ Vh) {
    __shared__ alignas(16) unsigned short AsS[128 * 32];
    __shared__ alignas(16) unsigned short BsS[128 * 32];
    floatx4 acc[4][4] = {};
    int bid = blockIdx.x;
    int tid = threadIdx.x;
    int wv = tid >> 6, ln = tid & 63;
    int quad = ln >> 4, l16 = ln & 15;
    int wr = wv >> 1, wc = wv & 1;
    const float ASCALE = 0.3535533905932738f * 1.4426950408889634f;  // 1/sqrt(8)*log2(e)

    if (bid < 192) {
        int n0 = (bid % 12) * 128, m0 = (bid / 12) * 128;
        gemm_core<true>(hs_bf, 2048, Wqkv_t, 512, m0, n0, AsS, BsS, acc);
        #pragma unroll
        for (int i = 0; i < 4; ++i) {
            int tok = m0 + wr * 64 + i * 16 + l16;      // lane-varying token
            int b_ = tok >> 10, nn = tok & 1023;
            int vcol = (nn & ~31) | vslot(nn & 31);     // permuted V column
            #pragma unroll
            for (int j = 0; j < 4; ++j) {
                int colb = n0 + wc * 64 + j * 16 + quad * 4;   // wave-uniform
                float vv[4];
                #pragma unroll
                for (int r = 0; r < 4; ++r) vv[r] = acc[i][j][r] + bqkv[colb + r];
                if (colb < 512) {
                    int h = colb >> 3, c = colb & 7;
                    ushortx4 w = { f2bf(vv[0] * ASCALE), f2bf(vv[1] * ASCALE),
                                   f2bf(vv[2] * ASCALE), f2bf(vv[3] * ASCALE) };
                    *(ushortx4*)(Qh + ((size_t)(b_ * 64 + h) * 1024 + nn) * 8 + c) = w;
                } else if (colb < 1024) {
                    int cc = colb - 512, h = cc >> 3, c = cc & 7;
                    ushortx4 w = { f2bf(vv[0]), f2bf(vv[1]), f2bf(vv[2]), f2bf(vv[3]) };
                    *(ushortx4*)(Kh + ((size_t)(b_ * 64 + h) * KROWS + nn) * 8 + c) = w;
                } else {
                    int cc = colb - 1024, h = cc >> 3, c = cc & 7;
                    #pragma unroll
                    for (int r = 0; r < 4; ++r)
                        Vh[((size_t)(b_ * 64 + h) * 16 + c + r) * KROWS + vcol] = f2bf(vv[r]);
                }
            }
        }
    } else {
        int idx = bid - 192;
        int n0 = (idx % 8) * 128, m0 = (idx / 8) * 128;
        gemm_core<true>(enc_bf, 154, Wakv_t, 768, m0, n0, AsS, BsS, acc);
        #pragma unroll
        for (int i = 0; i < 4; ++i) {
            int rg = m0 + wr * 64 + i * 16 + l16;       // lane-varying enc token
            bool ok = rg < 154;
            int b_ = rg >= 77;
            int jj = rg - 77 * b_;
            int e = 1024 + jj;
            int vcol = (e & ~31) | vslot(e & 31);       // permuted V column
            #pragma unroll
            for (int j = 0; j < 4; ++j) {
                int colb = n0 + wc * 64 + j * 16 + quad * 4;
                float vv[4];
                #pragma unroll
                for (int r = 0; r < 4; ++r) vv[r] = acc[i][j][r] + bakv[colb + r];
                if (colb < 512) {
                    int h = colb >> 3, c = colb & 7;
                    if (ok) {
                        ushortx4 w = { f2bf(vv[0]), f2bf(vv[1]), f2bf(vv[2]), f2bf(vv[3]) };
                        *(ushortx4*)(Kh + ((size_t)(b_ * 64 + h) * KROWS + 1024 + jj) * 8 + c) = w;
                    }
                } else {
                    int cc = colb - 512, h = cc >> 3, c = cc & 7;
                    if (ok) {
                        #pragma unroll
                        for (int r = 0; r < 4; ++r)
                            Vh[((size_t)(b_ * 64 + h) * 16 + c + r) * KROWS + vcol] = f2bf(vv[r]);
                    }
                }
            }
        }
    }
}

// ---------------------------------------------------------------- out-projection
__global__ __launch_bounds__(256) void gemm_out(
        const unsigned short* __restrict__ Wo_t, const unsigned short* __restrict__ AO,
        const float* __restrict__ bias, const float* __restrict__ resid,
        float* __restrict__ out) {
    __shared__ alignas(16) unsigned short AsS[128 * 32];
    __shared__ alignas(16) unsigned short BsS[128 * 32];
    floatx4 acc[4][4] = {};
    int tid = threadIdx.x;
    int wv = tid >> 6, ln = tid & 63;
    int quad = ln >> 4, l16 = ln & 15;
    int wr = wv >> 1, wc = wv & 1;
    int n0 = blockIdx.x * 128, m0 = blockIdx.y * 128;
    gemm_core<false>(Wo_t, 512, AO, 512, m0, n0, AsS, BsS, acc);
    #pragma unroll
    for (int i = 0; i < 4; ++i) {
        int cbase = m0 + wr * 64 + i * 16 + quad * 4;
        #pragma unroll
        for (int j = 0; j < 4; ++j) {
            int ng = n0 + wc * 64 + j * 16 + l16;
            int b = ng >> 10, n = ng & 1023;
            float4 res = *(const float4*)(resid + ((size_t)(b * 1024 + n)) * 512 + cbase);
            float rr[4] = {res.x, res.y, res.z, res.w};
            #pragma unroll
            for (int r = 0; r < 4; ++r) {
                int c = cbase + r;
                out[((size_t)(b * 512 + c)) * 1024 + n] = acc[i][j][r] + bias[c] + rr[r];
            }
        }
    }
}

// ---------------------------------------------------------------- MFMA flash attention
// Block = (b, h, qtile of 128); 4 waves x 32 queries (2 16q-subtiles sharing K/V).
// S = mfma(K,Q) -> thread holds S[kv=quad*4+r][q=l16] (s0) and +16 (s1): with
// Vh kv-columns PERMUTED (vslot), [exp2(s0),exp2(s1)] IS the PV A-frag.
// Zero LDS, zero barriers in the main loop. Fixed-max softmax (m=0, exact);
// l = sum(p) via ones-row at V ch=8.
__global__ __launch_bounds__(256) void attn_mfma(
        const unsigned short* __restrict__ Qh,   // [2][64][1024][8]
        const unsigned short* __restrict__ Kh,   // [2][64][KROWS][8]
        const unsigned short* __restrict__ Vh,   // [2][64][16][KROWS] (kv-permuted)
        unsigned short* __restrict__ AO) {       // [2048][512]
    int x = blockIdx.x;
    int h = x & 63, qt = (x >> 6) & 7, b = x >> 9;
    int tid = threadIdx.x, wv = tid >> 6, ln = tid & 63;
    int quad = ln >> 4, l16 = ln & 15;
    int q0r = qt * 128 + wv * 32;
    int bh = b * 64 + h;

    short8 qa = {}, qb = {};
    if (quad == 0) {
        qa = *(const short8*)(Qh + ((size_t)bh * 1024 + q0r + l16) * 8);
        qb = *(const short8*)(Qh + ((size_t)bh * 1024 + q0r + 16 + l16) * 8);
    }
    const unsigned short* Kb = Kh + (size_t)bh * KROWS * 8;
    const unsigned short* Vb = Vh + ((size_t)bh * 16 + l16) * KROWS;

    floatx4 acca = {}, accb = {};

    for (int base = 0; base < 1088; base += 32) {
        short8 k0 = *(const short8*)(Kb + (size_t)(base + l16) * 8);
        short8 k1 = *(const short8*)(Kb + (size_t)(base + 16 + l16) * 8);
        short8 vf = *(const short8*)(Vb + base + quad * 8);
        floatx4 z = {};
        floatx4 s0a = __builtin_amdgcn_mfma_f32_16x16x32_bf16(k0, qa, z, 0, 0, 0);
        floatx4 s1a = __builtin_amdgcn_mfma_f32_16x16x32_bf16(k1, qa, z, 0, 0, 0);
        floatx4 s0b = __builtin_amdgcn_mfma_f32_16x16x32_bf16(k0, qb, z, 0, 0, 0);
        floatx4 s1b = __builtin_amdgcn_mfma_f32_16x16x32_bf16(k1, qb, z, 0, 0, 0);
        union { ushortx4 hlf[2]; short8 s; } ua, ub;
        #pragma unroll
        for (int r = 0; r < 4; ++r) {
            ua.hlf[0][r] = rtzbf(__builtin_amdgcn_exp2f(s0a[r]));
            ua.hlf[1][r] = rtzbf(__builtin_amdgcn_exp2f(s1a[r]));
            ub.hlf[0][r] = rtzbf(__builtin_amdgcn_exp2f(s0b[r]));
            ub.hlf[1][r] = rtzbf(__builtin_amdgcn_exp2f(s1b[r]));
        }
        acca = __builtin_amdgcn_mfma_f32_16x16x32_bf16(ua.s, vf, acca, 0, 0, 0);
        accb = __builtin_amdgcn_mfma_f32_16x16x32_bf16(ub.s, vf, accb, 0, 0, 0);
    }
    {   // tail chunk base=1088: valid kvrel 0..12 (13 of 32)
        short8 k0 = *(const short8*)(Kb + (size_t)(1088 + l16) * 8);
        short8 vf = *(const short8*)(Vb + 1088 + quad * 8);
        floatx4 z = {};
        floatx4 s0a = __builtin_amdgcn_mfma_f32_16x16x32_bf16(k0, qa, z, 0, 0, 0);
        floatx4 s0b = __builtin_amdgcn_mfma_f32_16x16x32_bf16(k0, qb, z, 0, 0, 0);
        union { ushortx4 hlf[2]; short8 s; } ua, ub;
        #pragma unroll
        for (int r = 0; r < 4; ++r) {
            bool valid = (quad * 4 + r) < 13;
            ua.hlf[0][r] = valid ? rtzbf(__builtin_amdgcn_exp2f(s0a[r])) : (unsigned short)0;
            ua.hlf[1][r] = 0;
            ub.hlf[0][r] = valid ? rtzbf(__builtin_amdgcn_exp2f(s0b[r])) : (unsigned short)0;
            ub.hlf[1][r] = 0;
        }
        acca = __builtin_amdgcn_mfma_f32_16x16x32_bf16(ua.s, vf, acca, 0, 0, 0);
        accb = __builtin_amdgcn_mfma_f32_16x16x32_bf16(ub.s, vf, accb, 0, 0, 0);
    }

    #pragma unroll
    for (int r = 0; r < 4; ++r) {
        float la = __shfl(acca[r], (ln & 48) + 8, 64);    // l from ones-column (ch=8)
        float lb = __shfl(accb[r], (ln & 48) + 8, 64);
        if (l16 < 8) {
            AO[((size_t)(b * 1024 + q0r + quad * 4 + r)) * 512 + h * 8 + l16] =
                f2bf(acca[r] / la);
            AO[((size_t)(b * 1024 + q0r + 16 + quad * 4 + r)) * 512 + h * 8 + l16] =
                f2bf(accb[r] / lb);
        }
    }
}

// ---------------------------------------------------------------- launcher
extern "C" void kernel_launch(void* const* d_in, const int* in_sizes, int n_in,
                              void* d_out, int out_size, void* d_ws, size_t ws_size,
                              hipStream_t stream) {
    const float* x    = (const float*)d_in[0];
    const float* enc  = (const float*)d_in[1];
    const float* gn_s = (const float*)d_in[2];
    const float* gn_b = (const float*)d_in[3];
    const float* ln_s = (const float*)d_in[4];
    const float* ln_b = (const float*)d_in[5];
    const float* Wq  = (const float*)d_in[6];   const float* bq  = (const float*)d_in[7];
    const float* Wk  = (const float*)d_in[8];   const float* bk  = (const float*)d_in[9];
    const float* Wv  = (const float*)d_in[10];  const float* bv  = (const float*)d_in[11];
    const float* Wak = (const float*)d_in[12];  const float* bak = (const float*)d_in[13];
    const float* Wav = (const float*)d_in[14];  const float* bav = (const float*)d_in[15];
    const float* Wo  = (const float*)d_in[16];  const float* bo  = (const float*)d_in[17];
    float* out = (float*)d_out;

    char* p = (char*)d_ws;
    auto alloc = [&](size_t bytes) { char* r = p; p += (bytes + 255) & ~255ULL; return r; };
    unsigned short* hs_bf  = (unsigned short*)alloc((size_t)2048 * 512 * 2);
    unsigned short* enc_bf = (unsigned short*)alloc((size_t)154 * 768 * 2);
    unsigned short* Wqkv_t = (unsigned short*)alloc((size_t)1536 * 512 * 2);
    unsigned short* Wakv_t = (unsigned short*)alloc((size_t)1024 * 768 * 2);
    unsigned short* Wo_t   = (unsigned short*)alloc((size_t)512 * 512 * 2);
    float* bqkv = (float*)alloc(1536 * 4);
    float* bakv = (float*)alloc(1024 * 4);
    unsigned short* Qh = (unsigned short*)alloc((size_t)2 * 64 * 1024 * 8 * 2);
    unsigned short* Kh = (unsigned short*)alloc((size_t)2 * 64 * KROWS * 8 * 2);
    unsigned short* Vh = (unsigned short*)alloc((size_t)2 * 64 * 16 * KROWS * 2);
    unsigned short* AO = (unsigned short*)alloc((size_t)2048 * 512 * 2);

    prep_all<<<2580, 256, 0, stream>>>(
        Wq, Wk, Wv, Wak, Wav, Wo, bq, bk, bv, bak, bav,
        enc, ln_s, ln_b, x, gn_s, gn_b,
        Wqkv_t, Wakv_t, Wo_t, bqkv, bakv, enc_bf, hs_bf, Vh);

    proj_gemm<<<208, 256, 0, stream>>>(
        hs_bf, enc_bf, Wqkv_t, Wakv_t, bqkv, bakv, Qh, Kh, Vh);

    attn_mfma<<<BSZ * NHEAD * 8, 256, 0, stream>>>(Qh, Kh, Vh, AO);

    gemm_out<<<dim3(16, 4), 256, 0, stream>>>(Wo_t, AO, bo, x, out);

    (void)in_sizes; (void)n_in; (void)out_size; (void)ws_size;
}

// Round 10
// 150.133 us; speedup vs baseline: 2.4722x; 1.0274x over previous
//
#include <hip/hip_runtime.h>
#include <math.h>

// Problem constants
#define BSZ   2
#define NTOK  1024          // 32*32
#define CDIM  512
#define SENC  77
#define SKV   1101          // 77 + 1024 (order: self rows 0..1023, enc rows 1024..1100)
#define KROWS 1120          // padded KV rows (35 chunks of 32)
#define ENCD  768
#define NHEAD 64
#define DHEAD 8

typedef short short8 __attribute__((ext_vector_type(8)));
typedef float floatx4 __attribute__((ext_vector_type(4)));
typedef unsigned short ushortx4 __attribute__((ext_vector_type(4)));

__device__ __forceinline__ unsigned short f2bf(float f) {
    union { float f; unsigned int u; } v; v.f = f;
    unsigned int r = v.u + 0x7FFF + ((v.u >> 16) & 1);   // RNE
    return (unsigned short)(r >> 16);
}
__device__ __forceinline__ unsigned short rtzbf(float f) {
    return (unsigned short)(__float_as_uint(f) >> 16);   // RTZ (cancels in softmax norm)
}
// kv-column permutation so S-MFMA output regs ARE the PV A-frag
__device__ __forceinline__ int vslot(int kr) {
    return ((kr & 12) << 1) | ((kr & 16) >> 2) | (kr & 3);
}

// C-style casts: clang only allows addrspacecast via C-style
__device__ __forceinline__ void gld16(const void* g, void* l) {
    __builtin_amdgcn_global_load_lds(
        (const __attribute__((address_space(1))) unsigned int*)g,
        (__attribute__((address_space(3))) unsigned int*)l,
        16, 0, 0);
}

// ---------------------------------------------------------------- reductions
__device__ __forceinline__ float block_reduce_sum(float v) {
    #pragma unroll
    for (int off = 32; off > 0; off >>= 1) v += __shfl_down(v, off, 64);
    __shared__ float tmp[4];
    int lane = threadIdx.x & 63, wid = threadIdx.x >> 6;
    if (lane == 0) tmp[wid] = v;
    __syncthreads();
    if (wid == 0) {
        float r = (lane < 4) ? tmp[lane] : 0.f;
        r += __shfl_down(r, 2, 64);
        r += __shfl_down(r, 1, 64);
        if (lane == 0) tmp[0] = r;
    }
    __syncthreads();
    float out = tmp[0];
    __syncthreads();
    return out;
}

// ---------------------------------------------------------------- prep device parts
__device__ void layernorm_dev(int row, const float* __restrict__ x,
                              const float* __restrict__ sc, const float* __restrict__ bi,
                              unsigned short* __restrict__ out) {
    const float* xp = x + (size_t)row * ENCD;
    unsigned short* op = out + (size_t)row * ENCD;
    int t = threadIdx.x;
    float v0 = xp[t], v1 = xp[t + 256], v2 = xp[t + 512];
    float mu = block_reduce_sum(v0 + v1 + v2) * (1.f / ENCD);
    float d0 = v0 - mu, d1 = v1 - mu, d2 = v2 - mu;
    float var = block_reduce_sum(d0 * d0 + d1 * d1 + d2 * d2) * (1.f / ENCD);
    float rstd = rsqrtf(var + 1e-5f);
    op[t]       = f2bf(d0 * rstd * sc[t]       + bi[t]);
    op[t + 256] = f2bf(d1 * rstd * sc[t + 256] + bi[t + 256]);
    op[t + 512] = f2bf(d2 * rstd * sc[t + 512] + bi[t + 512]);
}

// single-pass register-resident GroupNorm
__device__ void groupnorm_dev(int bg, const float* __restrict__ x,
                              const float* __restrict__ sc, const float* __restrict__ bi,
                              unsigned short* __restrict__ out) {
    int b = bg >> 5, g = bg & 31;
    const float* xp = x + (size_t)b * NTOK * CDIM + g * 16;
    unsigned short* op = out + (size_t)b * NTOK * CDIM + g * 16;
    int t = threadIdx.x;
    int q = t & 3;

    float4 v[16];
    #pragma unroll
    for (int it = 0; it < 16; ++it) {
        int idx = t + it * 256;
        int n = idx >> 2;
        v[it] = *(const float4*)(xp + n * CDIM + q * 4);
    }
    float s = 0.f, ss = 0.f;
    #pragma unroll
    for (int it = 0; it < 16; ++it) {
        s  += (v[it].x + v[it].y) + (v[it].z + v[it].w);
        ss += (v[it].x * v[it].x + v[it].y * v[it].y)
            + (v[it].z * v[it].z + v[it].w * v[it].w);
    }
    float mu  = block_reduce_sum(s)  * (1.f / 16384.f);
    float msq = block_reduce_sum(ss) * (1.f / 16384.f);
    float rstd = rsqrtf(msq - mu * mu + 1e-5f);

    float4 s4 = *(const float4*)(sc + g * 16 + q * 4);
    float4 b4 = *(const float4*)(bi + g * 16 + q * 4);
    #pragma unroll
    for (int it = 0; it < 16; ++it) {
        int idx = t + it * 256;
        int n = idx >> 2;
        ushortx4 o;
        o[0] = f2bf((v[it].x - mu) * rstd * s4.x + b4.x);
        o[1] = f2bf((v[it].y - mu) * rstd * s4.y + b4.y);
        o[2] = f2bf((v[it].z - mu) * rstd * s4.z + b4.z);
        o[3] = f2bf((v[it].w - mu) * rstd * s4.w + b4.w);
        *(ushortx4*)(op + n * CDIM + q * 4) = o;
    }
}

// transpose+cast one 32x32 tile: W[K][N] fp32 -> Wt[N+roff][K] bf16
__device__ void tcast_dev(const float* __restrict__ W, unsigned short* __restrict__ Wt,
                          int K, int N, int roff, int local) {
    __shared__ float t[32][33];
    int bn = (local & 15) * 32, bk = (local >> 4) * 32;
    int lx = threadIdx.x & 31, ly = threadIdx.x >> 5;
    #pragma unroll
    for (int r = 0; r < 4; ++r)
        t[ly + 8 * r][lx] = W[(size_t)(bk + ly + 8 * r) * N + bn + lx];
    __syncthreads();
    #pragma unroll
    for (int r = 0; r < 4; ++r)
        Wt[(size_t)(roff + bn + ly + 8 * r) * K + bk + lx] = f2bf(t[lx][ly + 8 * r]);
}

// ---------------------------------------------------------------- fused preprocessing
__global__ __launch_bounds__(256) void prep_all(
        const float* __restrict__ Wq, const float* __restrict__ Wk, const float* __restrict__ Wv,
        const float* __restrict__ Wak, const float* __restrict__ Wav, const float* __restrict__ Wo,
        const float* __restrict__ bq, const float* __restrict__ bk, const float* __restrict__ bv,
        const float* __restrict__ bak, const float* __restrict__ bav,
        const float* __restrict__ enc, const float* __restrict__ ln_s, const float* __restrict__ ln_b,
        const float* __restrict__ x, const float* __restrict__ gn_s, const float* __restrict__ gn_b,
        unsigned short* __restrict__ Wqkv_t, unsigned short* __restrict__ Wakv_t,
        unsigned short* __restrict__ Wo_t,
        float* __restrict__ bqkv, float* __restrict__ bakv,
        unsigned short* __restrict__ enc_bf, unsigned short* __restrict__ hs_bf,
        unsigned short* __restrict__ Vh) {
    int bid = blockIdx.x;
    if (bid < 256)        tcast_dev(Wq,  Wqkv_t, 512, 512, 0,    bid);
    else if (bid < 512)   tcast_dev(Wk,  Wqkv_t, 512, 512, 512,  bid - 256);
    else if (bid < 768)   tcast_dev(Wv,  Wqkv_t, 512, 512, 1024, bid - 512);
    else if (bid < 1152)  tcast_dev(Wak, Wakv_t, 768, 512, 0,    bid - 768);
    else if (bid < 1536)  tcast_dev(Wav, Wakv_t, 768, 512, 512,  bid - 1152);
    else if (bid < 1792)  tcast_dev(Wo,  Wo_t,   512, 512, 0,    bid - 1536);
    else if (bid < 1802) {
        int i = (bid - 1792) * 256 + threadIdx.x;
        if (i < 512)        bqkv[i] = bq[i];
        else if (i < 1024)  bqkv[i] = bk[i - 512];
        else if (i < 1536)  bqkv[i] = bv[i - 1024];
        else if (i < 2048)  bakv[i - 1536] = bak[i - 1536];
        else if (i < 2560)  bakv[i - 1536] = bav[i - 2048];
    }
    else if (bid < 1956)  layernorm_dev(bid - 1802, enc, ln_s, ln_b, enc_bf);
    else if (bid < 2020)  groupnorm_dev(bid - 1956, x, gn_s, gn_b, hs_bf);
    else {
        // ones-row (ch=8) of Vh for the l=sum(p) trick (permutation-invariant)
        int i = (bid - 2020) * 256 + threadIdx.x;   // [0, 143360)
        int g = i / KROWS, kv = i - g * KROWS;      // g = b*64+h
        Vh[((size_t)g * 16 + 8) * KROWS + kv] = 0x3F80;  // bf16 1.0
    }
}

// ---------------------------------------------------------------- shared GEMM core
// 64x128 tile, 4 waves 2x2 (wave tile 32x64), 16x16x32 bf16 MFMA.
// SWAP=false: acc[i][j] = C[row-in-regs][col-in-lanes]
// SWAP=true : acc[i][j] = C[col-in-regs][row-in-lanes]
template <bool SWAP>
__device__ __forceinline__ void gemm_core64(
        const unsigned short* __restrict__ A, int Mv,
        const unsigned short* __restrict__ Bt, int K,
        int m0, int n0, unsigned short* AsS, unsigned short* BsS,
        floatx4 (&acc)[2][4]) {
    int tid = threadIdx.x;
    int wv = tid >> 6, ln = tid & 63;
    int quad = ln >> 4, l16 = ln & 15;
    int wr = wv >> 1, wc = wv & 1;

    for (int k0 = 0; k0 < K; k0 += 32) {
        {   // A: 64 rows x 32 cols = 256 x 16B
            int r = tid >> 2, sg = tid & 3;
            int row = m0 + r; if (row > Mv - 1) row = Mv - 1;
            gld16((const void*)(A + (size_t)row * K + k0 + sg * 8),
                  (void*)((char*)AsS + tid * 16));
        }
        #pragma unroll
        for (int it = 0; it < 2; ++it) {   // B: 128 rows x 32 cols
            int c = it * 256 + tid;
            int r = c >> 2, sg = c & 3;
            gld16((const void*)(Bt + (size_t)(n0 + r) * K + k0 + sg * 8),
                  (void*)((char*)BsS + c * 16));
        }
        __syncthreads();
        short8 af[2], bf[4];
        #pragma unroll
        for (int i = 0; i < 2; ++i)
            af[i] = *(const short8*)(AsS + (wr * 32 + i * 16 + l16) * 32 + quad * 8);
        #pragma unroll
        for (int j = 0; j < 4; ++j)
            bf[j] = *(const short8*)(BsS + (wc * 64 + j * 16 + l16) * 32 + quad * 8);
        #pragma unroll
        for (int i = 0; i < 2; ++i)
            #pragma unroll
            for (int j = 0; j < 4; ++j)
                acc[i][j] = SWAP
                    ? __builtin_amdgcn_mfma_f32_16x16x32_bf16(bf[j], af[i], acc[i][j], 0, 0, 0)
                    : __builtin_amdgcn_mfma_f32_16x16x32_bf16(af[i], bf[j], acc[i][j], 0, 0, 0);
        __syncthreads();
    }
}

// ---------------------------------------------------------------- merged projections
// blocks [0,384): QKV [2048,512]x[512,1536] -> head-major Qh/Kh/Vh (64-row tiles)
// blocks [384,408): enc KV [154,768]x[768,1024] -> Kh/Vh rows 1024+
__global__ __launch_bounds__(256) void proj_gemm(
        const unsigned short* __restrict__ hs_bf, const unsigned short* __restrict__ enc_bf,
        const unsigned short* __restrict__ Wqkv_t, const unsigned short* __restrict__ Wakv_t,
        const float* __restrict__ bqkv, const float* __restrict__ bakv,
        unsigned short* __restrict__ Qh, unsigned short* __restrict__ Kh,
        unsigned short* __restrict__ Vh) {
    __shared__ alignas(16) unsigned short AsS[64 * 32];
    __shared__ alignas(16) unsigned short BsS[128 * 32];
    floatx4 acc[2][4] = {};
    int bid = blockIdx.x;
    int tid = threadIdx.x;
    int wv = tid >> 6, ln = tid & 63;
    int quad = ln >> 4, l16 = ln & 15;
    int wr = wv >> 1, wc = wv & 1;
    const float ASCALE = 0.3535533905932738f * 1.4426950408889634f;  // 1/sqrt(8)*log2(e)

    if (bid < 384) {
        int n0 = (bid % 12) * 128, m0 = (bid / 12) * 64;
        gemm_core64<true>(hs_bf, 2048, Wqkv_t, 512, m0, n0, AsS, BsS, acc);
        #pragma unroll
        for (int i = 0; i < 2; ++i) {
            int tok = m0 + wr * 32 + i * 16 + l16;      // lane-varying token
            int b_ = tok >> 10, nn = tok & 1023;
            int vcol = (nn & ~31) | vslot(nn & 31);     // permuted V column
            #pragma unroll
            for (int j = 0; j < 4; ++j) {
                int colb = n0 + wc * 64 + j * 16 + quad * 4;   // wave-uniform
                float vv[4];
                #pragma unroll
                for (int r = 0; r < 4; ++r) vv[r] = acc[i][j][r] + bqkv[colb + r];
                if (colb < 512) {
                    int h = colb >> 3, c = colb & 7;
                    ushortx4 w = { f2bf(vv[0] * ASCALE), f2bf(vv[1] * ASCALE),
                                   f2bf(vv[2] * ASCALE), f2bf(vv[3] * ASCALE) };
                    *(ushortx4*)(Qh + ((size_t)(b_ * 64 + h) * 1024 + nn) * 8 + c) = w;
                } else if (colb < 1024) {
                    int cc = colb - 512, h = cc >> 3, c = cc & 7;
                    ushortx4 w = { f2bf(vv[0]), f2bf(vv[1]), f2bf(vv[2]), f2bf(vv[3]) };
                    *(ushortx4*)(Kh + ((size_t)(b_ * 64 + h) * KROWS + nn) * 8 + c) = w;
                } else {
                    int cc = colb - 1024, h = cc >> 3, c = cc & 7;
                    #pragma unroll
                    for (int r = 0; r < 4; ++r)
                        Vh[((size_t)(b_ * 64 + h) * 16 + c + r) * KROWS + vcol] = f2bf(vv[r]);
                }
            }
        }
    } else {
        int idx = bid - 384;
        int n0 = (idx % 8) * 128, m0 = (idx / 8) * 64;
        gemm_core64<true>(enc_bf, 154, Wakv_t, 768, m0, n0, AsS, BsS, acc);
        #pragma unroll
        for (int i = 0; i < 2; ++i) {
            int rg = m0 + wr * 32 + i * 16 + l16;       // lane-varying enc token
            bool ok = rg < 154;
            int b_ = rg >= 77;
            int jj = rg - 77 * b_;
            int e = 1024 + jj;
            int vcol = (e & ~31) | vslot(e & 31);       // permuted V column
            #pragma unroll
            for (int j = 0; j < 4; ++j) {
                int colb = n0 + wc * 64 + j * 16 + quad * 4;
                float vv[4];
                #pragma unroll
                for (int r = 0; r < 4; ++r) vv[r] = acc[i][j][r] + bakv[colb + r];
                if (colb < 512) {
                    int h = colb >> 3, c = colb & 7;
                    if (ok) {
                        ushortx4 w = { f2bf(vv[0]), f2bf(vv[1]), f2bf(vv[2]), f2bf(vv[3]) };
                        *(ushortx4*)(Kh + ((size_t)(b_ * 64 + h) * KROWS + 1024 + jj) * 8 + c) = w;
                    }
                } else {
                    int cc = colb - 512, h = cc >> 3, c = cc & 7;
                    if (ok) {
                        #pragma unroll
                        for (int r = 0; r < 4; ++r)
                            Vh[((size_t)(b_ * 64 + h) * 16 + c + r) * KROWS + vcol] = f2bf(vv[r]);
                    }
                }
            }
        }
    }
}

// ---------------------------------------------------------------- out-projection
// C^T: A=Wo_t [512,512], Bt=AO [2048,512] -> out[(b*512+c)*1024+n] + bias + residual
// grid (16, 8): 128 blocks (64-row tiles over channels)
__global__ __launch_bounds__(256) void gemm_out(
        const unsigned short* __restrict__ Wo_t, const unsigned short* __restrict__ AO,
        const float* __restrict__ bias, const float* __restrict__ resid,
        float* __restrict__ out) {
    __shared__ alignas(16) unsigned short AsS[64 * 32];
    __shared__ alignas(16) unsigned short BsS[128 * 32];
    floatx4 acc[2][4] = {};
    int tid = threadIdx.x;
    int wv = tid >> 6, ln = tid & 63;
    int quad = ln >> 4, l16 = ln & 15;
    int wr = wv >> 1, wc = wv & 1;
    int n0 = blockIdx.x * 128, m0 = blockIdx.y * 64;
    gemm_core64<false>(Wo_t, 512, AO, 512, m0, n0, AsS, BsS, acc);
    #pragma unroll
    for (int i = 0; i < 2; ++i) {
        int cbase = m0 + wr * 32 + i * 16 + quad * 4;
        #pragma unroll
        for (int j = 0; j < 4; ++j) {
            int ng = n0 + wc * 64 + j * 16 + l16;
            int b = ng >> 10, n = ng & 1023;
            float4 res = *(const float4*)(resid + ((size_t)(b * 1024 + n)) * 512 + cbase);
            float rr[4] = {res.x, res.y, res.z, res.w};
            #pragma unroll
            for (int r = 0; r < 4; ++r) {
                int c = cbase + r;
                out[((size_t)(b * 512 + c)) * 1024 + n] = acc[i][j][r] + bias[c] + rr[r];
            }
        }
    }
}

// ---------------------------------------------------------------- MFMA flash attention
// Zero LDS / zero barriers in the main loop (V kv-permuted so S-output = PV A-frag).
__global__ __launch_bounds__(256) void attn_mfma(
        const unsigned short* __restrict__ Qh,   // [2][64][1024][8]
        const unsigned short* __restrict__ Kh,   // [2][64][KROWS][8]
        const unsigned short* __restrict__ Vh,   // [2][64][16][KROWS] (kv-permuted)
        unsigned short* __restrict__ AO) {       // [2048][512]
    int x = blockIdx.x;
    int h = x & 63, qt = (x >> 6) & 7, b = x >> 9;
    int tid = threadIdx.x, wv = tid >> 6, ln = tid & 63;
    int quad = ln >> 4, l16 = ln & 15;
    int q0r = qt * 128 + wv * 32;
    int bh = b * 64 + h;

    short8 qa = {}, qb = {};
    if (quad == 0) {
        qa = *(const short8*)(Qh + ((size_t)bh * 1024 + q0r + l16) * 8);
        qb = *(const short8*)(Qh + ((size_t)bh * 1024 + q0r + 16 + l16) * 8);
    }
    const unsigned short* Kb = Kh + (size_t)bh * KROWS * 8;
    const unsigned short* Vb = Vh + ((size_t)bh * 16 + l16) * KROWS;

    floatx4 acca = {}, accb = {};

    for (int base = 0; base < 1088; base += 32) {
        short8 k0 = *(const short8*)(Kb + (size_t)(base + l16) * 8);
        short8 k1 = *(const short8*)(Kb + (size_t)(base + 16 + l16) * 8);
        short8 vf = *(const short8*)(Vb + base + quad * 8);
        floatx4 z = {};
        floatx4 s0a = __builtin_amdgcn_mfma_f32_16x16x32_bf16(k0, qa, z, 0, 0, 0);
        floatx4 s1a = __builtin_amdgcn_mfma_f32_16x16x32_bf16(k1, qa, z, 0, 0, 0);
        floatx4 s0b = __builtin_amdgcn_mfma_f32_16x16x32_bf16(k0, qb, z, 0, 0, 0);
        floatx4 s1b = __builtin_amdgcn_mfma_f32_16x16x32_bf16(k1, qb, z, 0, 0, 0);
        union { ushortx4 hlf[2]; short8 s; } ua, ub;
        #pragma unroll
        for (int r = 0; r < 4; ++r) {
            ua.hlf[0][r] = rtzbf(__builtin_amdgcn_exp2f(s0a[r]));
            ua.hlf[1][r] = rtzbf(__builtin_amdgcn_exp2f(s1a[r]));
            ub.hlf[0][r] = rtzbf(__builtin_amdgcn_exp2f(s0b[r]));
            ub.hlf[1][r] = rtzbf(__builtin_amdgcn_exp2f(s1b[r]));
        }
        acca = __builtin_amdgcn_mfma_f32_16x16x32_bf16(ua.s, vf, acca, 0, 0, 0);
        accb = __builtin_amdgcn_mfma_f32_16x16x32_bf16(ub.s, vf, accb, 0, 0, 0);
    }
    {   // tail chunk base=1088: valid kvrel 0..12 (13 of 32)
        short8 k0 = *(const short8*)(Kb + (size_t)(1088 + l16) * 8);
        short8 vf = *(const short8*)(Vb + 1088 + quad * 8);
        floatx4 z = {};
        floatx4 s0a = __builtin_amdgcn_mfma_f32_16x16x32_bf16(k0, qa, z, 0, 0, 0);
        floatx4 s0b = __builtin_amdgcn_mfma_f32_16x16x32_bf16(k0, qb, z, 0, 0, 0);
        union { ushortx4 hlf[2]; short8 s; } ua, ub;
        #pragma unroll
        for (int r = 0; r < 4; ++r) {
            bool valid = (quad * 4 + r) < 13;
            ua.hlf[0][r] = valid ? rtzbf(__builtin_amdgcn_exp2f(s0a[r])) : (unsigned short)0;
            ua.hlf[1][r] = 0;
            ub.hlf[0][r] = valid ? rtzbf(__builtin_amdgcn_exp2f(s0b[r])) : (unsigned short)0;
            ub.hlf[1][r] = 0;
        }
        acca = __builtin_amdgcn_mfma_f32_16x16x32_bf16(ua.s, vf, acca, 0, 0, 0);
        accb = __builtin_amdgcn_mfma_f32_16x16x32_bf16(ub.s, vf, accb, 0, 0, 0);
    }

    #pragma unroll
    for (int r = 0; r < 4; ++r) {
        float la = __shfl(acca[r], (ln & 48) + 8, 64);    // l from ones-column (ch=8)
        float lb = __shfl(accb[r], (ln & 48) + 8, 64);
        if (l16 < 8) {
            AO[((size_t)(b * 1024 + q0r + quad * 4 + r)) * 512 + h * 8 + l16] =
                f2bf(acca[r] / la);
            AO[((size_t)(b * 1024 + q0r + 16 + quad * 4 + r)) * 512 + h * 8 + l16] =
                f2bf(accb[r] / lb);
        }
    }
}

// ---------------------------------------------------------------- launcher
extern "C" void kernel_launch(void* const* d_in, const int* in_sizes, int n_in,
                              void* d_out, int out_size, void* d_ws, size_t ws_size,
                              hipStream_t stream) {
    const float* x    = (const float*)d_in[0];
    const float* enc  = (const float*)d_in[1];
    const float* gn_s = (const float*)d_in[2];
    const float* gn_b = (const float*)d_in[3];
    const float* ln_s = (const float*)d_in[4];
    const float* ln_b = (const float*)d_in[5];
    const float* Wq  = (const float*)d_in[6];   const float* bq  = (const float*)d_in[7];
    const float* Wk  = (const float*)d_in[8];   const float* bk  = (const float*)d_in[9];
    const float* Wv  = (const float*)d_in[10];  const float* bv  = (const float*)d_in[11];
    const float* Wak = (const float*)d_in[12];  const float* bak = (const float*)d_in[13];
    const float* Wav = (const float*)d_in[14];  const float* bav = (const float*)d_in[15];
    const float* Wo  = (const float*)d_in[16];  const float* bo  = (const float*)d_in[17];
    float* out = (float*)d_out;

    char* p = (char*)d_ws;
    auto alloc = [&](size_t bytes) { char* r = p; p += (bytes + 255) & ~255ULL; return r; };
    unsigned short* hs_bf  = (unsigned short*)alloc((size_t)2048 * 512 * 2);
    unsigned short* enc_bf = (unsigned short*)alloc((size_t)154 * 768 * 2);
    unsigned short* Wqkv_t = (unsigned short*)alloc((size_t)1536 * 512 * 2);
    unsigned short* Wakv_t = (unsigned short*)alloc((size_t)1024 * 768 * 2);
    unsigned short* Wo_t   = (unsigned short*)alloc((size_t)512 * 512 * 2);
    float* bqkv = (float*)alloc(1536 * 4);
    float* bakv = (float*)alloc(1024 * 4);
    unsigned short* Qh = (unsigned short*)alloc((size_t)2 * 64 * 1024 * 8 * 2);
    unsigned short* Kh = (unsigned short*)alloc((size_t)2 * 64 * KROWS * 8 * 2);
    unsigned short* Vh = (unsigned short*)alloc((size_t)2 * 64 * 16 * KROWS * 2);
    unsigned short* AO = (unsigned short*)alloc((size_t)2048 * 512 * 2);

    prep_all<<<2580, 256, 0, stream>>>(
        Wq, Wk, Wv, Wak, Wav, Wo, bq, bk, bv, bak, bav,
        enc, ln_s, ln_b, x, gn_s, gn_b,
        Wqkv_t, Wakv_t, Wo_t, bqkv, bakv, enc_bf, hs_bf, Vh);

    proj_gemm<<<408, 256, 0, stream>>>(
        hs_bf, enc_bf, Wqkv_t, Wakv_t, bqkv, bakv, Qh, Kh, Vh);

    attn_mfma<<<BSZ * NHEAD * 8, 256, 0, stream>>>(Qh, Kh, Vh, AO);

    gemm_out<<<dim3(16, 8), 256, 0, stream>>>(Wo_t, AO, bo, x, out);

    (void)in_sizes; (void)n_in; (void)out_size; (void)ws_size;
}